// Round 1
// baseline (2137.545 us; speedup 1.0000x reference)
//
#include <hip/hip_runtime.h>
#include <hip/hip_bf16.h>
#include <math.h>

// Transformer-XL RelMultiHeadAttn, fp32 correctness-first baseline.
// Shapes: QLEN=1024, BSZ=4, D_MODEL=1024, N_HEAD=16, D_HEAD=64, RLEN=1025.
// Pipeline:
//   K1 gemm_qkv : ws_qkv[5121+pad, 3072] = [w(4096 rows); r(1025 rows)] @ W_qkv
//   K2 attn     : per (b, n, i-tile64): online-softmax attention using
//                 score(i,j) = Q'_i . (K_j + R_{1024+j-i}) * 0.125, causal mask
//                 (rel_shift closed form; masked region never read validly)
//   K3 gemm_o   : ws_ao[4096,1024] = attn_vec @ W_o
//   K4 ln       : out = LayerNorm(w + ws_ao) * gamma + beta

#define QLEN 1024
#define BSZ 4
#define DMODEL 1024
#define NHEAD 16
#define DHEAD 64
#define RLEN 1025
#define MW (QLEN*BSZ)        // 4096
#define M1 (MW + RLEN)       // 5121
#define N1 (3*NHEAD*DHEAD)   // 3072

// ---------------- GEMM1: [w;r] @ W_qkv -> C[M1, 3072] ----------------
__global__ __launch_bounds__(256) void gemm_qkv(const float* __restrict__ w,
                                                const float* __restrict__ r,
                                                const float* __restrict__ B,
                                                float* __restrict__ C)
{
    __shared__ float As[16][65];
    __shared__ float Bs[16][64];
    const int n0 = blockIdx.x * 64;
    const int m0 = blockIdx.y * 64;
    const int t  = threadIdx.x;
    const int tx = t & 15, ty = t >> 4;
    const int arow = t >> 2, ak0 = (t & 3) * 4;   // A stage: 64 rows x 16 k
    const int bkk  = t >> 4, bn0 = (t & 15) * 4;  // B stage: 16 k x 64 n
    const int grow = m0 + arow;
    float acc[4][4] = {};
    for (int kt = 0; kt < 64; ++kt) {
        const int k0 = kt * 16;
        float4 av = make_float4(0.f, 0.f, 0.f, 0.f);
        if (grow < MW)      av = *(const float4*)(w + (size_t)grow * 1024 + k0 + ak0);
        else if (grow < M1) av = *(const float4*)(r + (size_t)(grow - MW) * 1024 + k0 + ak0);
        float4 bv = *(const float4*)(B + (size_t)(k0 + bkk) * N1 + n0 + bn0);
        __syncthreads();   // previous iteration's LDS reads done
        As[ak0+0][arow] = av.x; As[ak0+1][arow] = av.y;
        As[ak0+2][arow] = av.z; As[ak0+3][arow] = av.w;
        *(float4*)&Bs[bkk][bn0] = bv;
        __syncthreads();
#pragma unroll
        for (int kk = 0; kk < 16; ++kk) {
            float a[4], b[4];
#pragma unroll
            for (int u = 0; u < 4; ++u) a[u] = As[kk][ty + 16*u];
#pragma unroll
            for (int u = 0; u < 4; ++u) b[u] = Bs[kk][tx + 16*u];
#pragma unroll
            for (int i = 0; i < 4; ++i)
#pragma unroll
                for (int j = 0; j < 4; ++j) acc[i][j] += a[i] * b[j];
        }
    }
#pragma unroll
    for (int i = 0; i < 4; ++i) {
        const int m = m0 + ty + 16*i;
        if (m < M1) {
#pragma unroll
            for (int j = 0; j < 4; ++j)
                C[(size_t)m * N1 + n0 + tx + 16*j] = acc[i][j];
        }
    }
}

// ---------------- GEMM3: attn_vec @ W_o -> C[4096, 1024] ----------------
__global__ __launch_bounds__(256) void gemm_o(const float* __restrict__ A,
                                              const float* __restrict__ B,
                                              float* __restrict__ C)
{
    __shared__ float As[16][65];
    __shared__ float Bs[16][64];
    const int n0 = blockIdx.x * 64;
    const int m0 = blockIdx.y * 64;
    const int t  = threadIdx.x;
    const int tx = t & 15, ty = t >> 4;
    const int arow = t >> 2, ak0 = (t & 3) * 4;
    const int bkk  = t >> 4, bn0 = (t & 15) * 4;
    const int grow = m0 + arow;
    float acc[4][4] = {};
    for (int kt = 0; kt < 64; ++kt) {
        const int k0 = kt * 16;
        float4 av = *(const float4*)(A + (size_t)grow * 1024 + k0 + ak0);
        float4 bv = *(const float4*)(B + (size_t)(k0 + bkk) * 1024 + n0 + bn0);
        __syncthreads();
        As[ak0+0][arow] = av.x; As[ak0+1][arow] = av.y;
        As[ak0+2][arow] = av.z; As[ak0+3][arow] = av.w;
        *(float4*)&Bs[bkk][bn0] = bv;
        __syncthreads();
#pragma unroll
        for (int kk = 0; kk < 16; ++kk) {
            float a[4], b[4];
#pragma unroll
            for (int u = 0; u < 4; ++u) a[u] = As[kk][ty + 16*u];
#pragma unroll
            for (int u = 0; u < 4; ++u) b[u] = Bs[kk][tx + 16*u];
#pragma unroll
            for (int i = 0; i < 4; ++i)
#pragma unroll
                for (int j = 0; j < 4; ++j) acc[i][j] += a[i] * b[j];
        }
    }
#pragma unroll
    for (int i = 0; i < 4; ++i) {
        const int m = m0 + ty + 16*i;
#pragma unroll
        for (int j = 0; j < 4; ++j)
            C[(size_t)m * 1024 + n0 + tx + 16*j] = acc[i][j];
    }
}

// ---------------- Attention ----------------
// grid = (16 i-tiles, 64 bn).  block = 256 threads.
// thread t: row ii = t>>2 within i-tile, quarter g = t&3 owns jj in [g*16,g*16+16)
// for scores and d in [g*16, g*16+16) for the PV accumulator.
__global__ __launch_bounds__(256) void attn_kernel(const float* __restrict__ qkv,
                                                   float* __restrict__ av)
{
    __shared__ float Qs[64][68];
    __shared__ float Ks[64][68];
    __shared__ float Vs[64][68];
    __shared__ float Ps[64][68];
    __shared__ float Rs[127][68];

    const int it = blockIdx.x;
    const int bn = blockIdx.y;
    const int b  = bn >> 4;
    const int n  = bn & 15;
    const int t  = threadIdx.x;
    const int i0 = it * 64;
    const int ii = t >> 2;
    const int g  = t & 3;

    // load Q' = w_head_q + r_head_q[-1]  (q-section cols [0,1024))
    const float* rq = qkv + (size_t)(MW + RLEN - 1) * N1 + n * 64;  // row 5120
#pragma unroll
    for (int rep = 0; rep < 4; ++rep) {
        const int idx = t + rep * 256;        // 0..1023
        const int qi = idx >> 4, d4 = idx & 15;
        float4 qv = *(const float4*)(qkv + (size_t)((i0 + qi) * 4 + b) * N1 + n * 64 + d4 * 4);
        float4 rv = *(const float4*)(rq + d4 * 4);
        qv.x += rv.x; qv.y += rv.y; qv.z += rv.z; qv.w += rv.w;
        *(float4*)&Qs[qi][d4 * 4] = qv;
    }

    float m_run = -INFINITY, l_run = 0.f;
    float acc[16] = {};
    __syncthreads();

    for (int jt = 0; jt <= it; ++jt) {
        const int j0 = jt * 64;
        // stage K (cols 1024..2047) and V (cols 2048..3071)
#pragma unroll
        for (int rep = 0; rep < 4; ++rep) {
            const int idx = t + rep * 256;
            const int jj = idx >> 4, d4 = idx & 15;
            const size_t base = (size_t)((j0 + jj) * 4 + b) * N1 + 1024 + n * 64 + d4 * 4;
            *(float4*)&Ks[jj][d4 * 4] = *(const float4*)(qkv + base);
            *(float4*)&Vs[jj][d4 * 4] = *(const float4*)(qkv + base + 1024);
        }
        // stage R band: idx = ridx0 + rr covers all 1024 + j - i for this tile pair
        const int ridx0 = 1024 + j0 - i0 - 63;
        for (int l = t; l < 127 * 16; l += 256) {
            const int rr = l >> 4, d4 = l & 15;
            const int idx = ridx0 + rr;
            float4 rv = make_float4(0.f, 0.f, 0.f, 0.f);
            if (idx <= 1024)
                rv = *(const float4*)(qkv + (size_t)(MW + idx) * N1 + 1024 + n * 64 + d4 * 4);
            *(float4*)&Rs[rr][d4 * 4] = rv;
        }
        __syncthreads();

        // scores: s[u] = Q'_ii . (K_jj + R_{jj-ii+63}),  jj = g*16+u
        float s[16] = {};
        for (int d4 = 0; d4 < 16; ++d4) {
            const float4 q4 = *(const float4*)&Qs[ii][d4 * 4];
#pragma unroll
            for (int u = 0; u < 16; ++u) {
                const int jj = g * 16 + u;
                const int rr = jj - ii + 63;
                const float4 k4 = *(const float4*)&Ks[jj][d4 * 4];
                const float4 r4 = *(const float4*)&Rs[rr][d4 * 4];
                s[u] += q4.x * (k4.x + r4.x) + q4.y * (k4.y + r4.y)
                      + q4.z * (k4.z + r4.z) + q4.w * (k4.w + r4.w);
            }
        }
        // mask + scale + online softmax (4 threads per row cooperate)
        float tmax = -INFINITY;
#pragma unroll
        for (int u = 0; u < 16; ++u) {
            const int j = j0 + g * 16 + u;
            s[u] = (j > i0 + ii) ? -INFINITY : s[u] * 0.125f;
            tmax = fmaxf(tmax, s[u]);
        }
        tmax = fmaxf(tmax, __shfl_xor(tmax, 1));
        tmax = fmaxf(tmax, __shfl_xor(tmax, 2));
        const float m_new = fmaxf(m_run, tmax);
        const float corr  = __expf(m_run - m_new);
        float p[16];
        float psum = 0.f;
#pragma unroll
        for (int u = 0; u < 16; ++u) { p[u] = __expf(s[u] - m_new); psum += p[u]; }
        psum += __shfl_xor(psum, 1);
        psum += __shfl_xor(psum, 2);
        l_run = l_run * corr + psum;
        m_run = m_new;
#pragma unroll
        for (int d = 0; d < 16; ++d) acc[d] *= corr;
#pragma unroll
        for (int u4 = 0; u4 < 4; ++u4)
            *(float4*)&Ps[ii][g * 16 + u4 * 4] =
                make_float4(p[u4*4], p[u4*4+1], p[u4*4+2], p[u4*4+3]);
        __syncthreads();   // Ps visible to all (and K/V reads done before next stage)

        // PV: acc[d] += sum_jj P[ii][jj] * V[jj][g*16+d]
        for (int jj = 0; jj < 64; ++jj) {
            const float pv = Ps[ii][jj];
#pragma unroll
            for (int d4 = 0; d4 < 4; ++d4) {
                const float4 v4 = *(const float4*)&Vs[jj][g * 16 + d4 * 4];
                acc[d4*4+0] += pv * v4.x;
                acc[d4*4+1] += pv * v4.y;
                acc[d4*4+2] += pv * v4.z;
                acc[d4*4+3] += pv * v4.w;
            }
        }
        __syncthreads();   // PV reads done before next-iter staging overwrites
    }

    const float inv_l = 1.f / l_run;
    const size_t row = (size_t)((i0 + ii) * 4 + b);
#pragma unroll
    for (int d4 = 0; d4 < 4; ++d4) {
        float4 o = make_float4(acc[d4*4+0] * inv_l, acc[d4*4+1] * inv_l,
                               acc[d4*4+2] * inv_l, acc[d4*4+3] * inv_l);
        *(float4*)(av + row * 1024 + n * 64 + g * 16 + d4 * 4) = o;
    }
}

// ---------------- Residual + LayerNorm ----------------
__global__ __launch_bounds__(256) void ln_kernel(const float* __restrict__ w,
                                                 const float* __restrict__ ao,
                                                 const float* __restrict__ gamma,
                                                 const float* __restrict__ beta,
                                                 float* __restrict__ out)
{
    const int row = blockIdx.x;
    const int t = threadIdx.x;
    const size_t base = (size_t)row * 1024 + t * 4;
    const float4 xw = *(const float4*)(w + base);
    const float4 xa = *(const float4*)(ao + base);
    float x[4] = { xw.x + xa.x, xw.y + xa.y, xw.z + xa.z, xw.w + xa.w };
    float sum = x[0] + x[1] + x[2] + x[3];
    float sq  = x[0]*x[0] + x[1]*x[1] + x[2]*x[2] + x[3]*x[3];
#pragma unroll
    for (int off = 1; off < 64; off <<= 1) {
        sum += __shfl_xor(sum, off);
        sq  += __shfl_xor(sq, off);
    }
    __shared__ float ssum[4], ssq[4];
    const int wid = t >> 6;
    if ((t & 63) == 0) { ssum[wid] = sum; ssq[wid] = sq; }
    __syncthreads();
    sum = ssum[0] + ssum[1] + ssum[2] + ssum[3];
    sq  = ssq[0] + ssq[1] + ssq[2] + ssq[3];
    const float mu   = sum * (1.f / 1024.f);
    const float var  = sq * (1.f / 1024.f) - mu * mu;
    const float rstd = rsqrtf(var + 1e-5f);
    const float4 g4 = *(const float4*)(gamma + t * 4);
    const float4 b4 = *(const float4*)(beta + t * 4);
    float4 o;
    o.x = (x[0] - mu) * rstd * g4.x + b4.x;
    o.y = (x[1] - mu) * rstd * g4.y + b4.y;
    o.z = (x[2] - mu) * rstd * g4.z + b4.z;
    o.w = (x[3] - mu) * rstd * g4.w + b4.w;
    *(float4*)(out + base) = o;
}

extern "C" void kernel_launch(void* const* d_in, const int* in_sizes, int n_in,
                              void* d_out, int out_size, void* d_ws, size_t ws_size,
                              hipStream_t stream) {
    const float* w     = (const float*)d_in[0];
    const float* r     = (const float*)d_in[1];
    // d_in[2] attn_mask: deterministic causal mask, computed inline
    const float* Wqkv  = (const float*)d_in[3];
    const float* Wo    = (const float*)d_in[4];
    const float* gamma = (const float*)d_in[5];
    const float* beta  = (const float*)d_in[6];
    float* out = (float*)d_out;

    float* ws_qkv = (float*)d_ws;                          // [5184, 3072]
    float* ws_av  = ws_qkv + (size_t)5184 * N1;            // [4096, 1024]
    float* ws_ao  = ws_av + (size_t)4096 * 1024;           // [4096, 1024]

    gemm_qkv<<<dim3(48, 81), 256, 0, stream>>>(w, r, Wqkv, ws_qkv);
    attn_kernel<<<dim3(16, 64), 256, 0, stream>>>(ws_qkv, ws_av);
    gemm_o<<<dim3(16, 64), 256, 0, stream>>>(ws_av, Wo, ws_ao);
    ln_kernel<<<4096, 256, 0, stream>>>(w, ws_ao, gamma, beta, out);
}

// Round 3
// 481.359 us; speedup vs baseline: 4.4406x; 4.4406x over previous
//
#include <hip/hip_runtime.h>
#include <hip/hip_bf16.h>
#include <math.h>

// Transformer-XL RelMultiHeadAttn — bf16 MFMA pipeline.
// QLEN=1024 BSZ=4 DMODEL=1024 NHEAD=16 DHEAD=64 RLEN=1025
// score(i,j) = Q'_i.(K_j) + Q'_i.R_{1024+j-i} (rel-shift closed form), j<=i.
//
// Kernels:
//  zero_fill   : zero Rp pad rows + rq
//  cast_a      : [w;r] -> bf16 A[5248][1024] (rows >=5121 zero)
//  tcast       : W^T cast to bf16 (W_qkv -> Bqt[3072][1024], W_o -> Bot[1024][1024])
//  rq_kernel   : rq[n] = r[1024] @ W_qkv[:, n], n<1024 (split-K atomic)
//  gemm_qkv    : A @ Bqt^T (MFMA 16x16x32 bf16, 128^2 tile) with fused epilogue ->
//                Qp/Kp/Vp [(b,n)][i][d] bf16 (+rq for Q), Rp[n][64+idx][d] bf16
//  transpose_v : Vp -> Vt [(b,n)][d][j]
//  attn        : flash attention with banded rel term (MFMA), av bf16 [4096][1024]
//  gemm_o      : av @ Bot^T -> wsao f32
//  ln_kernel   : out = LayerNorm(w + wsao)*gamma + beta

typedef short bf16x8 __attribute__((ext_vector_type(8)));
typedef float f32x4  __attribute__((ext_vector_type(4)));
typedef unsigned short ushort_t;
typedef unsigned int uint_t;

#define MFMA(a, b, c) __builtin_amdgcn_mfma_f32_16x16x32_bf16((a), (b), (c), 0, 0, 0)

static __device__ __forceinline__ ushort_t f2bf(float f) {
    uint_t x = __float_as_uint(f);
    uint_t r = (x + 0x7fffu + ((x >> 16) & 1u)) >> 16;   // RTNE
    return (ushort_t)r;
}
static __device__ __forceinline__ float bf2f(ushort_t u) {
    return __uint_as_float(((uint_t)u) << 16);
}
static __device__ __forceinline__ f32x4 fzero() {
    f32x4 v; v[0] = 0.f; v[1] = 0.f; v[2] = 0.f; v[3] = 0.f; return v;
}

#define RP_LD 1216          // Rp rows per head: 64 zero-pad + 1025 valid + tail pad

// ---------------- zero fill (uint4 granularity) ----------------
__global__ __launch_bounds__(256) void zero_fill(uint4* __restrict__ p) {
    const size_t i = (size_t)blockIdx.x * 256 + threadIdx.x;
    p[i] = make_uint4(0u, 0u, 0u, 0u);
}

// ---------------- cast [w;r] -> bf16 A ----------------
__global__ __launch_bounds__(256) void cast_a(const float* __restrict__ w,
                                              const float* __restrict__ r,
                                              ushort_t* __restrict__ A) {
    const int row = blockIdx.x, t = threadIdx.x;
    float4 v = make_float4(0.f, 0.f, 0.f, 0.f);
    if (row < 4096)      v = *(const float4*)(w + (size_t)row * 1024 + t * 4);
    else if (row < 5121) v = *(const float4*)(r + (size_t)(row - 4096) * 1024 + t * 4);
    ushort4 o;
    o.x = f2bf(v.x); o.y = f2bf(v.y); o.z = f2bf(v.z); o.w = f2bf(v.w);
    *(ushort4*)(A + (size_t)row * 1024 + t * 4) = o;
}

// ---------------- transpose + cast: in f32 [R][C] -> out bf16 [C][R] ----------------
__global__ __launch_bounds__(256) void tcast(const float* __restrict__ in,
                                             ushort_t* __restrict__ out,
                                             int R, int C) {
    __shared__ float Ts[64][65];
    const int c0 = blockIdx.x * 64, r0 = blockIdx.y * 64, t = threadIdx.x;
#pragma unroll
    for (int rep = 0; rep < 4; ++rep) {
        const int idx = t + rep * 256;
        const int rr = idx >> 4, c4 = (idx & 15) * 4;
        *(float4*)&Ts[rr][c4] = *(const float4*)(in + (size_t)(r0 + rr) * C + c0 + c4);
    }
    __syncthreads();
#pragma unroll
    for (int rep = 0; rep < 2; ++rep) {
        const int idx = t + rep * 256;
        const int cc = idx >> 3, r8 = (idx & 7) * 8;
        alignas(16) ushort_t tmp[8];
#pragma unroll
        for (int e = 0; e < 8; ++e) tmp[e] = f2bf(Ts[r8 + e][cc]);
        *(uint4*)(out + (size_t)(c0 + cc) * R + r0 + r8) = *(const uint4*)tmp;
    }
}

// ---------------- rq[n] = r[1024] @ W_qkv[:, n] ----------------
__global__ __launch_bounds__(256) void rq_kernel(const float* __restrict__ r,
                                                 const float* __restrict__ Wqkv,
                                                 float* __restrict__ rq) {
    const int nb = blockIdx.x & 3, kb = blockIdx.x >> 2;
    const int n = nb * 256 + threadIdx.x;
    const float* rrow = r + (size_t)1024 * 1024;
    float s = 0.f;
    const int k0 = kb * 128;
    for (int k = k0; k < k0 + 128; ++k) s += rrow[k] * Wqkv[(size_t)k * 3072 + n];
    atomicAdd(rq + n, s);
}

// ---------------- GEMM1: A[5248][1024] @ Bqt[3072][1024]^T, fused epilogue ----------
__global__ __launch_bounds__(256) void gemm_qkv(const ushort_t* __restrict__ A,
                                                const ushort_t* __restrict__ Bt,
                                                const float* __restrict__ rq,
                                                ushort_t* __restrict__ Qp,
                                                ushort_t* __restrict__ Kp,
                                                ushort_t* __restrict__ Vp,
                                                ushort_t* __restrict__ Rp) {
    __shared__ alignas(16) ushort_t As[128][72];
    __shared__ alignas(16) ushort_t Bs[128][72];
    const int n0 = blockIdx.x * 128, m0 = blockIdx.y * 128;
    const int t = threadIdx.x, w = t >> 6, l = t & 63;
    const int wm = w >> 1, wn = w & 1, lr = l & 15, lk = l >> 4;
    f32x4 acc[4][4];
#pragma unroll
    for (int i = 0; i < 4; ++i)
#pragma unroll
        for (int j = 0; j < 4; ++j) acc[i][j] = fzero();

    for (int kt = 0; kt < 16; ++kt) {
        uint4 ra[4], rb[4];
#pragma unroll
        for (int rep = 0; rep < 4; ++rep) {
            const int idx = t + rep * 256;
            const int row = idx >> 3, c8 = (idx & 7) * 8;
            ra[rep] = *(const uint4*)(A  + (size_t)(m0 + row) * 1024 + kt * 64 + c8);
            rb[rep] = *(const uint4*)(Bt + (size_t)(n0 + row) * 1024 + kt * 64 + c8);
        }
        __syncthreads();
#pragma unroll
        for (int rep = 0; rep < 4; ++rep) {
            const int idx = t + rep * 256;
            const int row = idx >> 3, c8 = (idx & 7) * 8;
            *(uint4*)&As[row][c8] = ra[rep];
            *(uint4*)&Bs[row][c8] = rb[rep];
        }
        __syncthreads();
#pragma unroll
        for (int kk = 0; kk < 2; ++kk) {
            bf16x8 a[4], b[4];
#pragma unroll
            for (int mb = 0; mb < 4; ++mb)
                a[mb] = *(const bf16x8*)&As[wm * 64 + mb * 16 + lr][kk * 32 + lk * 8];
#pragma unroll
            for (int nb = 0; nb < 4; ++nb)
                b[nb] = *(const bf16x8*)&Bs[wn * 64 + nb * 16 + lr][kk * 32 + lk * 8];
#pragma unroll
            for (int mb = 0; mb < 4; ++mb)
#pragma unroll
                for (int nb = 0; nb < 4; ++nb)
                    acc[mb][nb] = MFMA(a[mb], b[nb], acc[mb][nb]);
        }
    }

    const int sec = n0 >> 10;   // 0:Q 1:K 2:V (sections 1024-aligned, tile-uniform)
#pragma unroll
    for (int mb = 0; mb < 4; ++mb) {
#pragma unroll
        for (int nb = 0; nb < 4; ++nb) {
#pragma unroll
            for (int r2 = 0; r2 < 4; ++r2) {
                const int m  = m0 + wm * 64 + mb * 16 + lk * 4 + r2;
                const int nn = n0 + wn * 64 + nb * 16 + lr;
                float v = acc[mb][nb][r2];
                if (sec == 0) {
                    if (m < 4096) {
                        v += rq[nn];
                        const int i = m >> 2, b = m & 3, nh = nn >> 6, d = nn & 63;
                        Qp[((size_t)(b * 16 + nh) * 1024 + i) * 64 + d] = f2bf(v);
                    }
                } else if (sec == 1) {
                    const int nk = nn - 1024, nh = nk >> 6, d = nk & 63;
                    if (m < 4096) {
                        const int i = m >> 2, b = m & 3;
                        Kp[((size_t)(b * 16 + nh) * 1024 + i) * 64 + d] = f2bf(v);
                    } else if (m <= 5120) {
                        const int idx = m - 4096;
                        Rp[((size_t)nh * RP_LD + 64 + idx) * 64 + d] = f2bf(v);
                    }
                } else {
                    if (m < 4096) {
                        const int nv = nn - 2048, nh = nv >> 6, d = nv & 63;
                        const int i = m >> 2, b = m & 3;
                        Vp[((size_t)(b * 16 + nh) * 1024 + i) * 64 + d] = f2bf(v);
                    }
                }
            }
        }
    }
}

// ---------------- V transpose: Vp[(bn)][j][d] -> Vt[(bn)][d][j] ----------------
__global__ __launch_bounds__(256) void transpose_v(const ushort_t* __restrict__ Vp,
                                                   ushort_t* __restrict__ Vt) {
    __shared__ ushort_t Ts[64][72];
    const int j0 = blockIdx.x * 64, bn = blockIdx.y, t = threadIdx.x;
#pragma unroll
    for (int rep = 0; rep < 2; ++rep) {
        const int idx = t + rep * 256;
        const int jj = idx >> 3, c8 = (idx & 7) * 8;
        *(uint4*)&Ts[jj][c8] = *(const uint4*)(Vp + ((size_t)bn * 1024 + j0 + jj) * 64 + c8);
    }
    __syncthreads();
#pragma unroll
    for (int rep = 0; rep < 2; ++rep) {
        const int idx = t + rep * 256;
        const int d = idx >> 3, j8 = (idx & 7) * 8;
        alignas(16) ushort_t tmp[8];
#pragma unroll
        for (int e = 0; e < 8; ++e) tmp[e] = Ts[j8 + e][d];
        *(uint4*)(Vt + ((size_t)bn * 64 + d) * 1024 + j0 + j8) = *(const uint4*)tmp;
    }
}

// ---------------- flash attention with banded rel term ----------------
// grid (16 i-tiles reversed, 64 bn). 4 waves x 16 rows each.
__global__ __launch_bounds__(256) void attn(const ushort_t* __restrict__ Qp,
                                            const ushort_t* __restrict__ Kp,
                                            const ushort_t* __restrict__ Vt,
                                            const ushort_t* __restrict__ Rp,
                                            ushort_t* __restrict__ av) {
    __shared__ alignas(16) ushort_t Ks [64][72];
    __shared__ alignas(16) ushort_t Vts[64][72];
    __shared__ alignas(16) ushort_t Pl [64][72];
    __shared__ alignas(16) ushort_t Rs [128][72];
    __shared__ alignas(16) ushort_t Dl [64][136];

    const int it = 15 - blockIdx.x, i0 = it * 64;
    const int bn = blockIdx.y, b = bn >> 4, n = bn & 15;
    const int t = threadIdx.x, w = t >> 6, l = t & 63, lr = l & 15, lk = l >> 4;

    // Q' fragments straight from global (row-major per (b,n))
    bf16x8 qf0, qf1;
    {
        const ushort_t* qb = Qp + ((size_t)bn * 1024 + i0 + w * 16 + lr) * 64 + lk * 8;
        qf0 = *(const bf16x8*)qb;
        qf1 = *(const bf16x8*)(qb + 32);
    }

    f32x4 O[4];
#pragma unroll
    for (int db = 0; db < 4; ++db) O[db] = fzero();
    float mrun[4] = {-INFINITY, -INFINITY, -INFINITY, -INFINITY};
    float lrun[4] = {0.f, 0.f, 0.f, 0.f};

    for (int jt = 0; jt <= it; ++jt) {
        const int j0 = jt * 64;
        const int rbase = 1025 + j0 - i0;   // Rp row (incl +64 pad shift) for band col 0
        // stage K (64 rows), Vt (64 rows), R band (128 rows); 128B per row
#pragma unroll
        for (int rep = 0; rep < 8; ++rep) {
            const int idx = t + rep * 256;
            const int rr = idx >> 3, c8 = (idx & 7) * 8;
            if (rr < 64) {
                *(uint4*)&Ks[rr][c8] =
                    *(const uint4*)(Kp + ((size_t)bn * 1024 + j0 + rr) * 64 + c8);
            } else if (rr < 128) {
                *(uint4*)&Vts[rr - 64][c8] =
                    *(const uint4*)(Vt + ((size_t)bn * 64 + (rr - 64)) * 1024 + j0 + c8);
            } else {
                *(uint4*)&Rs[rr - 128][c8] =
                    *(const uint4*)(Rp + ((size_t)n * RP_LD + rbase + (rr - 128)) * 64 + c8);
            }
        }
        __syncthreads();

        // banded rel term: wave w needs band cols [48-16w, 127-16w] -> 5 col-blocks
#pragma unroll
        for (int q5 = 0; q5 < 5; ++q5) {
            const int cb2 = (3 - w) + q5;
            f32x4 d = fzero();
            bf16x8 rb0 = *(const bf16x8*)&Rs[cb2 * 16 + lr][lk * 8];
            bf16x8 rb1 = *(const bf16x8*)&Rs[cb2 * 16 + lr][32 + lk * 8];
            d = MFMA(qf0, rb0, d);
            d = MFMA(qf1, rb1, d);
#pragma unroll
            for (int r2 = 0; r2 < 4; ++r2)
                Dl[w * 16 + lk * 4 + r2][cb2 * 16 + lr] = f2bf(d[r2]);
        }

        // ac = Q'.K^T
        float sv[4][4];
#pragma unroll
        for (int cb = 0; cb < 4; ++cb) {
            f32x4 s = fzero();
            bf16x8 kb0 = *(const bf16x8*)&Ks[cb * 16 + lr][lk * 8];
            bf16x8 kb1 = *(const bf16x8*)&Ks[cb * 16 + lr][32 + lk * 8];
            s = MFMA(qf0, kb0, s);
            s = MFMA(qf1, kb1, s);
#pragma unroll
            for (int r2 = 0; r2 < 4; ++r2) sv[cb][r2] = s[r2];
        }

        // assemble: add shifted band, scale, causal mask
#pragma unroll
        for (int r2 = 0; r2 < 4; ++r2) {
            const int ii = w * 16 + lk * 4 + r2;
            const int gi = i0 + ii;
#pragma unroll
            for (int cb = 0; cb < 4; ++cb) {
                const int jj = cb * 16 + lr;
                const float v = sv[cb][r2] + bf2f(Dl[ii][jj - ii + 63]);
                sv[cb][r2] = (j0 + jj > gi) ? -3.0e38f : v * 0.125f;
            }
        }

        // online softmax (16-lane groups hold a full row)
#pragma unroll
        for (int r2 = 0; r2 < 4; ++r2) {
            float tmax = fmaxf(fmaxf(sv[0][r2], sv[1][r2]), fmaxf(sv[2][r2], sv[3][r2]));
            tmax = fmaxf(tmax, __shfl_xor(tmax, 1));
            tmax = fmaxf(tmax, __shfl_xor(tmax, 2));
            tmax = fmaxf(tmax, __shfl_xor(tmax, 4));
            tmax = fmaxf(tmax, __shfl_xor(tmax, 8));
            const float mnew = fmaxf(mrun[r2], tmax);
            const float corr = __expf(mrun[r2] - mnew);
            mrun[r2] = mnew;
            float psum = 0.f;
#pragma unroll
            for (int cb = 0; cb < 4; ++cb) {
                const float p = __expf(sv[cb][r2] - mnew);
                sv[cb][r2] = p;
                psum += p;
            }
            psum += __shfl_xor(psum, 1);
            psum += __shfl_xor(psum, 2);
            psum += __shfl_xor(psum, 4);
            psum += __shfl_xor(psum, 8);
            lrun[r2] = lrun[r2] * corr + psum;
#pragma unroll
            for (int db = 0; db < 4; ++db) O[db][r2] *= corr;
#pragma unroll
            for (int cb = 0; cb < 4; ++cb)
                Pl[w * 16 + lk * 4 + r2][cb * 16 + lr] = f2bf(sv[cb][r2]);
        }

        // PV: O += P @ V   (A-frag from Pl rows, B-frag from V^T rows)
        bf16x8 pa0 = *(const bf16x8*)&Pl[w * 16 + lr][lk * 8];
        bf16x8 pa1 = *(const bf16x8*)&Pl[w * 16 + lr][32 + lk * 8];
#pragma unroll
        for (int db = 0; db < 4; ++db) {
            bf16x8 vb0 = *(const bf16x8*)&Vts[db * 16 + lr][lk * 8];
            bf16x8 vb1 = *(const bf16x8*)&Vts[db * 16 + lr][32 + lk * 8];
            O[db] = MFMA(pa0, vb0, O[db]);
            O[db] = MFMA(pa1, vb1, O[db]);
        }
        __syncthreads();
    }

#pragma unroll
    for (int r2 = 0; r2 < 4; ++r2) {
        const float inv = 1.0f / lrun[r2];
        const int row = (i0 + w * 16 + lk * 4 + r2) * 4 + b;
#pragma unroll
        for (int db = 0; db < 4; ++db)
            av[(size_t)row * 1024 + n * 64 + db * 16 + lr] = f2bf(O[db][r2] * inv);
    }
}

// ---------------- GEMM-O: av[4096][1024] @ Bot[1024][1024]^T -> f32 ----------------
__global__ __launch_bounds__(256) void gemm_o(const ushort_t* __restrict__ A,
                                              const ushort_t* __restrict__ Bt,
                                              float* __restrict__ C) {
    __shared__ alignas(16) ushort_t As[128][72];
    __shared__ alignas(16) ushort_t Bs[128][72];
    const int n0 = blockIdx.x * 128, m0 = blockIdx.y * 128;
    const int t = threadIdx.x, w = t >> 6, l = t & 63;
    const int wm = w >> 1, wn = w & 1, lr = l & 15, lk = l >> 4;
    f32x4 acc[4][4];
#pragma unroll
    for (int i = 0; i < 4; ++i)
#pragma unroll
        for (int j = 0; j < 4; ++j) acc[i][j] = fzero();

    for (int kt = 0; kt < 16; ++kt) {
        uint4 ra[4], rb[4];
#pragma unroll
        for (int rep = 0; rep < 4; ++rep) {
            const int idx = t + rep * 256;
            const int row = idx >> 3, c8 = (idx & 7) * 8;
            ra[rep] = *(const uint4*)(A  + (size_t)(m0 + row) * 1024 + kt * 64 + c8);
            rb[rep] = *(const uint4*)(Bt + (size_t)(n0 + row) * 1024 + kt * 64 + c8);
        }
        __syncthreads();
#pragma unroll
        for (int rep = 0; rep < 4; ++rep) {
            const int idx = t + rep * 256;
            const int row = idx >> 3, c8 = (idx & 7) * 8;
            *(uint4*)&As[row][c8] = ra[rep];
            *(uint4*)&Bs[row][c8] = rb[rep];
        }
        __syncthreads();
#pragma unroll
        for (int kk = 0; kk < 2; ++kk) {
            bf16x8 a[4], b[4];
#pragma unroll
            for (int mb = 0; mb < 4; ++mb)
                a[mb] = *(const bf16x8*)&As[wm * 64 + mb * 16 + lr][kk * 32 + lk * 8];
#pragma unroll
            for (int nb = 0; nb < 4; ++nb)
                b[nb] = *(const bf16x8*)&Bs[wn * 64 + nb * 16 + lr][kk * 32 + lk * 8];
#pragma unroll
            for (int mb = 0; mb < 4; ++mb)
#pragma unroll
                for (int nb = 0; nb < 4; ++nb)
                    acc[mb][nb] = MFMA(a[mb], b[nb], acc[mb][nb]);
        }
    }
#pragma unroll
    for (int mb = 0; mb < 4; ++mb)
#pragma unroll
        for (int nb = 0; nb < 4; ++nb)
#pragma unroll
            for (int r2 = 0; r2 < 4; ++r2)
                C[(size_t)(m0 + wm * 64 + mb * 16 + lk * 4 + r2) * 1024 +
                  n0 + wn * 64 + nb * 16 + lr] = acc[mb][nb][r2];
}

// ---------------- Residual + LayerNorm ----------------
__global__ __launch_bounds__(256) void ln_kernel(const float* __restrict__ w,
                                                 const float* __restrict__ ao,
                                                 const float* __restrict__ gamma,
                                                 const float* __restrict__ beta,
                                                 float* __restrict__ out) {
    const int row = blockIdx.x;
    const int t = threadIdx.x;
    const size_t base = (size_t)row * 1024 + t * 4;
    const float4 xw = *(const float4*)(w + base);
    const float4 xa = *(const float4*)(ao + base);
    float x[4] = { xw.x + xa.x, xw.y + xa.y, xw.z + xa.z, xw.w + xa.w };
    float sum = x[0] + x[1] + x[2] + x[3];
    float sq  = x[0]*x[0] + x[1]*x[1] + x[2]*x[2] + x[3]*x[3];
#pragma unroll
    for (int off = 1; off < 64; off <<= 1) {
        sum += __shfl_xor(sum, off);
        sq  += __shfl_xor(sq, off);
    }
    __shared__ float ssum[4], ssq[4];
    const int wid = t >> 6;
    if ((t & 63) == 0) { ssum[wid] = sum; ssq[wid] = sq; }
    __syncthreads();
    sum = ssum[0] + ssum[1] + ssum[2] + ssum[3];
    sq  = ssq[0] + ssq[1] + ssq[2] + ssq[3];
    const float mu   = sum * (1.f / 1024.f);
    const float var  = sq * (1.f / 1024.f) - mu * mu;
    const float rstd = rsqrtf(var + 1e-5f);
    const float4 g4 = *(const float4*)(gamma + t * 4);
    const float4 b4 = *(const float4*)(beta + t * 4);
    float4 o;
    o.x = (x[0] - mu) * rstd * g4.x + b4.x;
    o.y = (x[1] - mu) * rstd * g4.y + b4.y;
    o.z = (x[2] - mu) * rstd * g4.z + b4.z;
    o.w = (x[3] - mu) * rstd * g4.w + b4.w;
    *(float4*)(out + base) = o;
}

extern "C" void kernel_launch(void* const* d_in, const int* in_sizes, int n_in,
                              void* d_out, int out_size, void* d_ws, size_t ws_size,
                              hipStream_t stream) {
    const float* w     = (const float*)d_in[0];
    const float* r     = (const float*)d_in[1];
    // d_in[2] attn_mask: deterministic causal mask, computed inline
    const float* Wqkv  = (const float*)d_in[3];
    const float* Wo    = (const float*)d_in[4];
    const float* gamma = (const float*)d_in[5];
    const float* beta  = (const float*)d_in[6];
    float* out = (float*)d_out;

    char* base = (char*)d_ws;
    ushort_t* A16  = (ushort_t*)(base + 0);           // [5248][1024]
    ushort_t* Bqt  = (ushort_t*)(base + 10747904);    // [3072][1024]
    ushort_t* Bot  = (ushort_t*)(base + 17039360);    // [1024][1024]
    ushort_t* Qp   = (ushort_t*)(base + 19136512);    // [(b,n)][1024][64]
    ushort_t* Kp   = (ushort_t*)(base + 27525120);
    ushort_t* Vp   = (ushort_t*)(base + 35913728);
    ushort_t* Vtp  = (ushort_t*)(base + 44302336);    // [(b,n)][64][1024]
    ushort_t* Rp   = (ushort_t*)(base + 52690944);    // [16][1216][64]
    float*    rq   = (float*)   (base + 55181312);    // [1024]
    ushort_t* av   = (ushort_t*)(base + 55185408);    // [4096][1024]
    float*    wsao = (float*)   (base + 63574016);    // [4096][1024]

    // zero Rp (incl. pads) + rq: 2490368 + 4096 bytes = 155904 uint4
    zero_fill<<<609, 256, 0, stream>>>((uint4*)Rp);
    cast_a<<<5248, 256, 0, stream>>>(w, r, A16);
    tcast<<<dim3(48, 16), 256, 0, stream>>>(Wqkv, Bqt, 1024, 3072);
    tcast<<<dim3(16, 16), 256, 0, stream>>>(Wo, Bot, 1024, 1024);
    rq_kernel<<<32, 256, 0, stream>>>(r, Wqkv, rq);
    gemm_qkv<<<dim3(24, 41), 256, 0, stream>>>(A16, Bqt, rq, Qp, Kp, Vp, Rp);
    transpose_v<<<dim3(16, 64), 256, 0, stream>>>(Vp, Vtp);
    attn<<<dim3(16, 64), 256, 0, stream>>>(Qp, Kp, Vtp, Rp, av);
    gemm_o<<<dim3(8, 32), 256, 0, stream>>>(av, Bot, wsao);
    ln_kernel<<<4096, 256, 0, stream>>>(w, wsao, gamma, beta, out);
}

// Round 4
// 469.567 us; speedup vs baseline: 4.5522x; 1.0251x over previous
//
#include <hip/hip_runtime.h>
#include <hip/hip_bf16.h>
#include <math.h>

// Transformer-XL RelMultiHeadAttn — bf16 MFMA pipeline.
// QLEN=1024 BSZ=4 DMODEL=1024 NHEAD=16 DHEAD=64 RLEN=1025
// score(i,j) = Q'_i.(K_j) + Q'_i.R_{1024+j-i} (rel-shift closed form), j<=i.
//
// R3 changes (gemm_qkv only):
//  - LDS-staged epilogue -> coalesced uint4 global stores (was: scattered 2B
//    stores, 267MB HBM writes vs 27MB ideal)
//  - grid trimmed to 840 blocks (skip never-stored m>=4096 tiles of Q/V secs)
//  - bijective XCD swizzle (840 % 8 == 0)

typedef short bf16x8 __attribute__((ext_vector_type(8)));
typedef float f32x4  __attribute__((ext_vector_type(4)));
typedef unsigned short ushort_t;
typedef unsigned int uint_t;

#define MFMA(a, b, c) __builtin_amdgcn_mfma_f32_16x16x32_bf16((a), (b), (c), 0, 0, 0)

static __device__ __forceinline__ ushort_t f2bf(float f) {
    uint_t x = __float_as_uint(f);
    uint_t r = (x + 0x7fffu + ((x >> 16) & 1u)) >> 16;   // RTNE
    return (ushort_t)r;
}
static __device__ __forceinline__ float bf2f(ushort_t u) {
    return __uint_as_float(((uint_t)u) << 16);
}
static __device__ __forceinline__ f32x4 fzero() {
    f32x4 v; v[0] = 0.f; v[1] = 0.f; v[2] = 0.f; v[3] = 0.f; return v;
}

#define RP_LD 1216          // Rp rows per head: 64 zero-pad + 1025 valid + tail pad

// ---------------- zero fill (uint4 granularity) ----------------
__global__ __launch_bounds__(256) void zero_fill(uint4* __restrict__ p) {
    const size_t i = (size_t)blockIdx.x * 256 + threadIdx.x;
    p[i] = make_uint4(0u, 0u, 0u, 0u);
}

// ---------------- cast [w;r] -> bf16 A ----------------
__global__ __launch_bounds__(256) void cast_a(const float* __restrict__ w,
                                              const float* __restrict__ r,
                                              ushort_t* __restrict__ A) {
    const int row = blockIdx.x, t = threadIdx.x;
    float4 v = make_float4(0.f, 0.f, 0.f, 0.f);
    if (row < 4096)      v = *(const float4*)(w + (size_t)row * 1024 + t * 4);
    else if (row < 5121) v = *(const float4*)(r + (size_t)(row - 4096) * 1024 + t * 4);
    ushort4 o;
    o.x = f2bf(v.x); o.y = f2bf(v.y); o.z = f2bf(v.z); o.w = f2bf(v.w);
    *(ushort4*)(A + (size_t)row * 1024 + t * 4) = o;
}

// ---------------- transpose + cast: in f32 [R][C] -> out bf16 [C][R] ----------------
__global__ __launch_bounds__(256) void tcast(const float* __restrict__ in,
                                             ushort_t* __restrict__ out,
                                             int R, int C) {
    __shared__ float Ts[64][65];
    const int c0 = blockIdx.x * 64, r0 = blockIdx.y * 64, t = threadIdx.x;
#pragma unroll
    for (int rep = 0; rep < 4; ++rep) {
        const int idx = t + rep * 256;
        const int rr = idx >> 4, c4 = (idx & 15) * 4;
        *(float4*)&Ts[rr][c4] = *(const float4*)(in + (size_t)(r0 + rr) * C + c0 + c4);
    }
    __syncthreads();
#pragma unroll
    for (int rep = 0; rep < 2; ++rep) {
        const int idx = t + rep * 256;
        const int cc = idx >> 3, r8 = (idx & 7) * 8;
        alignas(16) ushort_t tmp[8];
#pragma unroll
        for (int e = 0; e < 8; ++e) tmp[e] = f2bf(Ts[r8 + e][cc]);
        *(uint4*)(out + (size_t)(c0 + cc) * R + r0 + r8) = *(const uint4*)tmp;
    }
}

// ---------------- rq[n] = r[1024] @ W_qkv[:, n] ----------------
__global__ __launch_bounds__(256) void rq_kernel(const float* __restrict__ r,
                                                 const float* __restrict__ Wqkv,
                                                 float* __restrict__ rq) {
    const int nb = blockIdx.x & 3, kb = blockIdx.x >> 2;
    const int n = nb * 256 + threadIdx.x;
    const float* rrow = r + (size_t)1024 * 1024;
    float s = 0.f;
    const int k0 = kb * 128;
    for (int k = k0; k < k0 + 128; ++k) s += rrow[k] * Wqkv[(size_t)k * 3072 + n];
    atomicAdd(rq + n, s);
}

// ---------------- GEMM1: A[5248][1024] @ Bqt[3072][1024]^T, fused epilogue ----------
// grid: 840 blocks 1-D.  y<32: x=0..23 (Q/K/V sections).  y>=32: x=8..15 (K sec -> R).
__global__ __launch_bounds__(256) void gemm_qkv(const ushort_t* __restrict__ A,
                                                const ushort_t* __restrict__ Bt,
                                                const float* __restrict__ rq,
                                                ushort_t* __restrict__ Qp,
                                                ushort_t* __restrict__ Kp,
                                                ushort_t* __restrict__ Vp,
                                                ushort_t* __restrict__ Rp) {
    __shared__ alignas(16) ushort_t smem[18432];   // As | Bs, reused as Sout
#define AS_(rr, cc) smem[(rr) * 72 + (cc)]
#define BS_(rr, cc) smem[9216 + (rr) * 72 + (cc)]

    // bijective XCD swizzle (840 = 8 * 105), then 1-D -> (x, y) tile decode
    const uint_t bid0 = blockIdx.x;
    const uint_t bid = (bid0 & 7u) * 105u + (bid0 >> 3);
    int xt, yt;
    if (bid < 768u) { yt = bid / 24u; xt = bid % 24u; }
    else            { const uint_t k = bid - 768u; yt = 32 + k / 8u; xt = 8 + k % 8u; }

    const int n0 = xt * 128, m0 = yt * 128;
    const int t = threadIdx.x, w = t >> 6, l = t & 63;
    const int wm = w >> 1, wn = w & 1, lr = l & 15, lk = l >> 4;
    f32x4 acc[4][4];
#pragma unroll
    for (int i = 0; i < 4; ++i)
#pragma unroll
        for (int j = 0; j < 4; ++j) acc[i][j] = fzero();

    for (int kt = 0; kt < 16; ++kt) {
        uint4 ra[4], rb[4];
#pragma unroll
        for (int rep = 0; rep < 4; ++rep) {
            const int idx = t + rep * 256;
            const int row = idx >> 3, c8 = (idx & 7) * 8;
            ra[rep] = *(const uint4*)(A  + (size_t)(m0 + row) * 1024 + kt * 64 + c8);
            rb[rep] = *(const uint4*)(Bt + (size_t)(n0 + row) * 1024 + kt * 64 + c8);
        }
        __syncthreads();
#pragma unroll
        for (int rep = 0; rep < 4; ++rep) {
            const int idx = t + rep * 256;
            const int row = idx >> 3, c8 = (idx & 7) * 8;
            *(uint4*)&AS_(row, c8) = ra[rep];
            *(uint4*)&BS_(row, c8) = rb[rep];
        }
        __syncthreads();
#pragma unroll
        for (int kk = 0; kk < 2; ++kk) {
            bf16x8 a[4], b[4];
#pragma unroll
            for (int mb = 0; mb < 4; ++mb)
                a[mb] = *(const bf16x8*)&AS_(wm * 64 + mb * 16 + lr, kk * 32 + lk * 8);
#pragma unroll
            for (int nb = 0; nb < 4; ++nb)
                b[nb] = *(const bf16x8*)&BS_(wn * 64 + nb * 16 + lr, kk * 32 + lk * 8);
#pragma unroll
            for (int mb = 0; mb < 4; ++mb)
#pragma unroll
                for (int nb = 0; nb < 4; ++nb)
                    acc[mb][nb] = MFMA(a[mb], b[nb], acc[mb][nb]);
        }
    }

    const int sec = n0 >> 10;   // 0:Q 1:K 2:V (tile-uniform)
    float rqv[4];
    if (sec == 0) {
#pragma unroll
        for (int nb = 0; nb < 4; ++nb)
            rqv[nb] = rq[n0 + wn * 64 + nb * 16 + lr];
    }
    __syncthreads();   // all frag reads done before smem reuse

    if (m0 < 4096) {
        // Fragment layout falls out as: b = r2, nh_local = wn, i_loc = wm*16+mb*4+lk,
        // d = nb*16+lr.  Stage 8 panels [b][nh][i(32)][d(64)] at pitch 72.
#pragma unroll
        for (int mb = 0; mb < 4; ++mb)
#pragma unroll
            for (int nb = 0; nb < 4; ++nb)
#pragma unroll
                for (int r2 = 0; r2 < 4; ++r2) {
                    float v = acc[mb][nb][r2];
                    if (sec == 0) v += rqv[nb];
                    smem[(r2 * 2 + wn) * 2304 + (wm * 16 + mb * 4 + lk) * 72 +
                         nb * 16 + lr] = f2bf(v);
                }
        __syncthreads();
        ushort_t* dst = (sec == 0) ? Qp : ((sec == 1) ? Kp : Vp);
        const int hbase = (n0 & 1023) >> 6;
        const int ibase = m0 >> 2;
#pragma unroll
        for (int rep = 0; rep < 8; ++rep) {
            const int f = rep * 256 + t;
            const int panel = f >> 8, il = (f >> 3) & 31, d8 = (f & 7) * 8;
            const int b = panel >> 1, nh = panel & 1;
            const uint4 v = *(const uint4*)&smem[panel * 2304 + il * 72 + d8];
            *(uint4*)(dst + ((size_t)(b * 16 + hbase + nh) * 1024 + ibase + il) * 64 + d8) = v;
        }
    } else {
        // R rows (sec==1 only reaches here): idx_local = wm*64+mb*16+lk*4+r2.
        // A rows >=5121 are zero, so tail writes are zeros (safe; zeros expected).
#pragma unroll
        for (int mb = 0; mb < 4; ++mb)
#pragma unroll
            for (int nb = 0; nb < 4; ++nb)
#pragma unroll
                for (int r2 = 0; r2 < 4; ++r2)
                    smem[wn * 9216 + (wm * 64 + mb * 16 + lk * 4 + r2) * 72 +
                         nb * 16 + lr] = f2bf(acc[mb][nb][r2]);
        __syncthreads();
        const int hbase = (n0 & 1023) >> 6;
        const int rbase0 = 64 + (m0 - 4096);
#pragma unroll
        for (int rep = 0; rep < 8; ++rep) {
            const int f = rep * 256 + t;
            const int nh = f >> 10, il = (f >> 3) & 127, d8 = (f & 7) * 8;
            const uint4 v = *(const uint4*)&smem[nh * 9216 + il * 72 + d8];
            *(uint4*)(Rp + ((size_t)(hbase + nh) * RP_LD + rbase0 + il) * 64 + d8) = v;
        }
    }
#undef AS_
#undef BS_
}

// ---------------- V transpose: Vp[(bn)][j][d] -> Vt[(bn)][d][j] ----------------
__global__ __launch_bounds__(256) void transpose_v(const ushort_t* __restrict__ Vp,
                                                   ushort_t* __restrict__ Vt) {
    __shared__ ushort_t Ts[64][72];
    const int j0 = blockIdx.x * 64, bn = blockIdx.y, t = threadIdx.x;
#pragma unroll
    for (int rep = 0; rep < 2; ++rep) {
        const int idx = t + rep * 256;
        const int jj = idx >> 3, c8 = (idx & 7) * 8;
        *(uint4*)&Ts[jj][c8] = *(const uint4*)(Vp + ((size_t)bn * 1024 + j0 + jj) * 64 + c8);
    }
    __syncthreads();
#pragma unroll
    for (int rep = 0; rep < 2; ++rep) {
        const int idx = t + rep * 256;
        const int d = idx >> 3, j8 = (idx & 7) * 8;
        alignas(16) ushort_t tmp[8];
#pragma unroll
        for (int e = 0; e < 8; ++e) tmp[e] = Ts[j8 + e][d];
        *(uint4*)(Vt + ((size_t)bn * 64 + d) * 1024 + j0 + j8) = *(const uint4*)tmp;
    }
}

// ---------------- flash attention with banded rel term ----------------
// grid (16 i-tiles reversed, 64 bn). 4 waves x 16 rows each.
__global__ __launch_bounds__(256) void attn(const ushort_t* __restrict__ Qp,
                                            const ushort_t* __restrict__ Kp,
                                            const ushort_t* __restrict__ Vt,
                                            const ushort_t* __restrict__ Rp,
                                            ushort_t* __restrict__ av) {
    __shared__ alignas(16) ushort_t Ks [64][72];
    __shared__ alignas(16) ushort_t Vts[64][72];
    __shared__ alignas(16) ushort_t Pl [64][72];
    __shared__ alignas(16) ushort_t Rs [128][72];
    __shared__ alignas(16) ushort_t Dl [64][136];

    const int it = 15 - blockIdx.x, i0 = it * 64;
    const int bn = blockIdx.y, b = bn >> 4, n = bn & 15;
    const int t = threadIdx.x, w = t >> 6, l = t & 63, lr = l & 15, lk = l >> 4;

    // Q' fragments straight from global (row-major per (b,n))
    bf16x8 qf0, qf1;
    {
        const ushort_t* qb = Qp + ((size_t)bn * 1024 + i0 + w * 16 + lr) * 64 + lk * 8;
        qf0 = *(const bf16x8*)qb;
        qf1 = *(const bf16x8*)(qb + 32);
    }

    f32x4 O[4];
#pragma unroll
    for (int db = 0; db < 4; ++db) O[db] = fzero();
    float mrun[4] = {-INFINITY, -INFINITY, -INFINITY, -INFINITY};
    float lrun[4] = {0.f, 0.f, 0.f, 0.f};

    for (int jt = 0; jt <= it; ++jt) {
        const int j0 = jt * 64;
        const int rbase = 1025 + j0 - i0;   // Rp row (incl +64 pad shift) for band col 0
        // stage K (64 rows), Vt (64 rows), R band (128 rows); 128B per row
#pragma unroll
        for (int rep = 0; rep < 8; ++rep) {
            const int idx = t + rep * 256;
            const int rr = idx >> 3, c8 = (idx & 7) * 8;
            if (rr < 64) {
                *(uint4*)&Ks[rr][c8] =
                    *(const uint4*)(Kp + ((size_t)bn * 1024 + j0 + rr) * 64 + c8);
            } else if (rr < 128) {
                *(uint4*)&Vts[rr - 64][c8] =
                    *(const uint4*)(Vt + ((size_t)bn * 64 + (rr - 64)) * 1024 + j0 + c8);
            } else {
                *(uint4*)&Rs[rr - 128][c8] =
                    *(const uint4*)(Rp + ((size_t)n * RP_LD + rbase + (rr - 128)) * 64 + c8);
            }
        }
        __syncthreads();

        // banded rel term: wave w needs band cols [48-16w, 127-16w] -> 5 col-blocks
#pragma unroll
        for (int q5 = 0; q5 < 5; ++q5) {
            const int cb2 = (3 - w) + q5;
            f32x4 d = fzero();
            bf16x8 rb0 = *(const bf16x8*)&Rs[cb2 * 16 + lr][lk * 8];
            bf16x8 rb1 = *(const bf16x8*)&Rs[cb2 * 16 + lr][32 + lk * 8];
            d = MFMA(qf0, rb0, d);
            d = MFMA(qf1, rb1, d);
#pragma unroll
            for (int r2 = 0; r2 < 4; ++r2)
                Dl[w * 16 + lk * 4 + r2][cb2 * 16 + lr] = f2bf(d[r2]);
        }

        // ac = Q'.K^T
        float sv[4][4];
#pragma unroll
        for (int cb = 0; cb < 4; ++cb) {
            f32x4 s = fzero();
            bf16x8 kb0 = *(const bf16x8*)&Ks[cb * 16 + lr][lk * 8];
            bf16x8 kb1 = *(const bf16x8*)&Ks[cb * 16 + lr][32 + lk * 8];
            s = MFMA(qf0, kb0, s);
            s = MFMA(qf1, kb1, s);
#pragma unroll
            for (int r2 = 0; r2 < 4; ++r2) sv[cb][r2] = s[r2];
        }

        // assemble: add shifted band, scale, causal mask
#pragma unroll
        for (int r2 = 0; r2 < 4; ++r2) {
            const int ii = w * 16 + lk * 4 + r2;
            const int gi = i0 + ii;
#pragma unroll
            for (int cb = 0; cb < 4; ++cb) {
                const int jj = cb * 16 + lr;
                const float v = sv[cb][r2] + bf2f(Dl[ii][jj - ii + 63]);
                sv[cb][r2] = (j0 + jj > gi) ? -3.0e38f : v * 0.125f;
            }
        }

        // online softmax (16-lane groups hold a full row)
#pragma unroll
        for (int r2 = 0; r2 < 4; ++r2) {
            float tmax = fmaxf(fmaxf(sv[0][r2], sv[1][r2]), fmaxf(sv[2][r2], sv[3][r2]));
            tmax = fmaxf(tmax, __shfl_xor(tmax, 1));
            tmax = fmaxf(tmax, __shfl_xor(tmax, 2));
            tmax = fmaxf(tmax, __shfl_xor(tmax, 4));
            tmax = fmaxf(tmax, __shfl_xor(tmax, 8));
            const float mnew = fmaxf(mrun[r2], tmax);
            const float corr = __expf(mrun[r2] - mnew);
            mrun[r2] = mnew;
            float psum = 0.f;
#pragma unroll
            for (int cb = 0; cb < 4; ++cb) {
                const float p = __expf(sv[cb][r2] - mnew);
                sv[cb][r2] = p;
                psum += p;
            }
            psum += __shfl_xor(psum, 1);
            psum += __shfl_xor(psum, 2);
            psum += __shfl_xor(psum, 4);
            psum += __shfl_xor(psum, 8);
            lrun[r2] = lrun[r2] * corr + psum;
#pragma unroll
            for (int db = 0; db < 4; ++db) O[db][r2] *= corr;
#pragma unroll
            for (int cb = 0; cb < 4; ++cb)
                Pl[w * 16 + lk * 4 + r2][cb * 16 + lr] = f2bf(sv[cb][r2]);
        }

        // PV: O += P @ V   (A-frag from Pl rows, B-frag from V^T rows)
        bf16x8 pa0 = *(const bf16x8*)&Pl[w * 16 + lr][lk * 8];
        bf16x8 pa1 = *(const bf16x8*)&Pl[w * 16 + lr][32 + lk * 8];
#pragma unroll
        for (int db = 0; db < 4; ++db) {
            bf16x8 vb0 = *(const bf16x8*)&Vts[db * 16 + lr][lk * 8];
            bf16x8 vb1 = *(const bf16x8*)&Vts[db * 16 + lr][32 + lk * 8];
            O[db] = MFMA(pa0, vb0, O[db]);
            O[db] = MFMA(pa1, vb1, O[db]);
        }
        __syncthreads();
    }

#pragma unroll
    for (int r2 = 0; r2 < 4; ++r2) {
        const float inv = 1.0f / lrun[r2];
        const int row = (i0 + w * 16 + lk * 4 + r2) * 4 + b;
#pragma unroll
        for (int db = 0; db < 4; ++db)
            av[(size_t)row * 1024 + n * 64 + db * 16 + lr] = f2bf(O[db][r2] * inv);
    }
}

// ---------------- GEMM-O: av[4096][1024] @ Bot[1024][1024]^T -> f32 ----------------
__global__ __launch_bounds__(256) void gemm_o(const ushort_t* __restrict__ A,
                                              const ushort_t* __restrict__ Bt,
                                              float* __restrict__ C) {
    __shared__ alignas(16) ushort_t As[128][72];
    __shared__ alignas(16) ushort_t Bs[128][72];
    const int n0 = blockIdx.x * 128, m0 = blockIdx.y * 128;
    const int t = threadIdx.x, w = t >> 6, l = t & 63;
    const int wm = w >> 1, wn = w & 1, lr = l & 15, lk = l >> 4;
    f32x4 acc[4][4];
#pragma unroll
    for (int i = 0; i < 4; ++i)
#pragma unroll
        for (int j = 0; j < 4; ++j) acc[i][j] = fzero();

    for (int kt = 0; kt < 16; ++kt) {
        uint4 ra[4], rb[4];
#pragma unroll
        for (int rep = 0; rep < 4; ++rep) {
            const int idx = t + rep * 256;
            const int row = idx >> 3, c8 = (idx & 7) * 8;
            ra[rep] = *(const uint4*)(A  + (size_t)(m0 + row) * 1024 + kt * 64 + c8);
            rb[rep] = *(const uint4*)(Bt + (size_t)(n0 + row) * 1024 + kt * 64 + c8);
        }
        __syncthreads();
#pragma unroll
        for (int rep = 0; rep < 4; ++rep) {
            const int idx = t + rep * 256;
            const int row = idx >> 3, c8 = (idx & 7) * 8;
            *(uint4*)&As[row][c8] = ra[rep];
            *(uint4*)&Bs[row][c8] = rb[rep];
        }
        __syncthreads();
#pragma unroll
        for (int kk = 0; kk < 2; ++kk) {
            bf16x8 a[4], b[4];
#pragma unroll
            for (int mb = 0; mb < 4; ++mb)
                a[mb] = *(const bf16x8*)&As[wm * 64 + mb * 16 + lr][kk * 32 + lk * 8];
#pragma unroll
            for (int nb = 0; nb < 4; ++nb)
                b[nb] = *(const bf16x8*)&Bs[wn * 64 + nb * 16 + lr][kk * 32 + lk * 8];
#pragma unroll
            for (int mb = 0; mb < 4; ++mb)
#pragma unroll
                for (int nb = 0; nb < 4; ++nb)
                    acc[mb][nb] = MFMA(a[mb], b[nb], acc[mb][nb]);
        }
    }
#pragma unroll
    for (int mb = 0; mb < 4; ++mb)
#pragma unroll
        for (int nb = 0; nb < 4; ++nb)
#pragma unroll
            for (int r2 = 0; r2 < 4; ++r2)
                C[(size_t)(m0 + wm * 64 + mb * 16 + lk * 4 + r2) * 1024 +
                  n0 + wn * 64 + nb * 16 + lr] = acc[mb][nb][r2];
}

// ---------------- Residual + LayerNorm ----------------
__global__ __launch_bounds__(256) void ln_kernel(const float* __restrict__ w,
                                                 const float* __restrict__ ao,
                                                 const float* __restrict__ gamma,
                                                 const float* __restrict__ beta,
                                                 float* __restrict__ out) {
    const int row = blockIdx.x;
    const int t = threadIdx.x;
    const size_t base = (size_t)row * 1024 + t * 4;
    const float4 xw = *(const float4*)(w + base);
    const float4 xa = *(const float4*)(ao + base);
    float x[4] = { xw.x + xa.x, xw.y + xa.y, xw.z + xa.z, xw.w + xa.w };
    float sum = x[0] + x[1] + x[2] + x[3];
    float sq  = x[0]*x[0] + x[1]*x[1] + x[2]*x[2] + x[3]*x[3];
#pragma unroll
    for (int off = 1; off < 64; off <<= 1) {
        sum += __shfl_xor(sum, off);
        sq  += __shfl_xor(sq, off);
    }
    __shared__ float ssum[4], ssq[4];
    const int wid = t >> 6;
    if ((t & 63) == 0) { ssum[wid] = sum; ssq[wid] = sq; }
    __syncthreads();
    sum = ssum[0] + ssum[1] + ssum[2] + ssum[3];
    sq  = ssq[0] + ssq[1] + ssq[2] + ssq[3];
    const float mu   = sum * (1.f / 1024.f);
    const float var  = sq * (1.f / 1024.f) - mu * mu;
    const float rstd = rsqrtf(var + 1e-5f);
    const float4 g4 = *(const float4*)(gamma + t * 4);
    const float4 b4 = *(const float4*)(beta + t * 4);
    float4 o;
    o.x = (x[0] - mu) * rstd * g4.x + b4.x;
    o.y = (x[1] - mu) * rstd * g4.y + b4.y;
    o.z = (x[2] - mu) * rstd * g4.z + b4.z;
    o.w = (x[3] - mu) * rstd * g4.w + b4.w;
    *(float4*)(out + base) = o;
}

extern "C" void kernel_launch(void* const* d_in, const int* in_sizes, int n_in,
                              void* d_out, int out_size, void* d_ws, size_t ws_size,
                              hipStream_t stream) {
    const float* w     = (const float*)d_in[0];
    const float* r     = (const float*)d_in[1];
    // d_in[2] attn_mask: deterministic causal mask, computed inline
    const float* Wqkv  = (const float*)d_in[3];
    const float* Wo    = (const float*)d_in[4];
    const float* gamma = (const float*)d_in[5];
    const float* beta  = (const float*)d_in[6];
    float* out = (float*)d_out;

    char* base = (char*)d_ws;
    ushort_t* A16  = (ushort_t*)(base + 0);           // [5248][1024]
    ushort_t* Bqt  = (ushort_t*)(base + 10747904);    // [3072][1024]
    ushort_t* Bot  = (ushort_t*)(base + 17039360);    // [1024][1024]
    ushort_t* Qp   = (ushort_t*)(base + 19136512);    // [(b,n)][1024][64]
    ushort_t* Kp   = (ushort_t*)(base + 27525120);
    ushort_t* Vp   = (ushort_t*)(base + 35913728);
    ushort_t* Vtp  = (ushort_t*)(base + 44302336);    // [(b,n)][64][1024]
    ushort_t* Rp   = (ushort_t*)(base + 52690944);    // [16][1216][64]
    float*    rq   = (float*)   (base + 55181312);    // [1024]
    ushort_t* av   = (ushort_t*)(base + 55185408);    // [4096][1024]
    float*    wsao = (float*)   (base + 63574016);    // [4096][1024]

    // zero Rp (incl. pads) + rq: 2490368 + 4096 bytes = 155904 uint4
    zero_fill<<<609, 256, 0, stream>>>((uint4*)Rp);
    cast_a<<<5248, 256, 0, stream>>>(w, r, A16);
    tcast<<<dim3(48, 16), 256, 0, stream>>>(Wqkv, Bqt, 1024, 3072);
    tcast<<<dim3(16, 16), 256, 0, stream>>>(Wo, Bot, 1024, 1024);
    rq_kernel<<<32, 256, 0, stream>>>(r, Wqkv, rq);
    gemm_qkv<<<840, 256, 0, stream>>>(A16, Bqt, rq, Qp, Kp, Vp, Rp);
    transpose_v<<<dim3(16, 64), 256, 0, stream>>>(Vp, Vtp);
    attn<<<dim3(16, 64), 256, 0, stream>>>(Qp, Kp, Vtp, Rp, av);
    gemm_o<<<dim3(8, 32), 256, 0, stream>>>(av, Bot, wsao);
    ln_kernel<<<4096, 256, 0, stream>>>(w, wsao, gamma, beta, out);
}

// Round 7
// 345.811 us; speedup vs baseline: 6.1812x; 1.3579x over previous
//
#include <hip/hip_runtime.h>
#include <hip/hip_bf16.h>
#include <math.h>

// Transformer-XL RelMultiHeadAttn — bf16 MFMA pipeline.
// QLEN=1024 BSZ=4 DMODEL=1024 NHEAD=16 DHEAD=64 RLEN=1025
// score(i,j) = Q'_i.(K_j) + Q'_i.R_{1024+j-i} (rel-shift closed form), j<=i.
//
// R5 changes (both GEMMs): m97-style staging — __builtin_amdgcn_global_load_lds
// width=16 into LINEAR [128][64] LDS tiles (wave-uniform dest + lane*16),
// 2 barriers/K-step. Replaces reg-roundtrip staging (174 TF, MfmaUtil 6.8%).

typedef short bf16x8 __attribute__((ext_vector_type(8)));
typedef float f32x4  __attribute__((ext_vector_type(4)));
typedef unsigned short ushort_t;
typedef unsigned int uint_t;

#define MFMA(a, b, c) __builtin_amdgcn_mfma_f32_16x16x32_bf16((a), (b), (c), 0, 0, 0)

static __device__ __forceinline__ ushort_t f2bf(float f) {
    uint_t x = __float_as_uint(f);
    uint_t r = (x + 0x7fffu + ((x >> 16) & 1u)) >> 16;   // RTNE
    return (ushort_t)r;
}
static __device__ __forceinline__ float bf2f(ushort_t u) {
    return __uint_as_float(((uint_t)u) << 16);
}
static __device__ __forceinline__ f32x4 fzero() {
    f32x4 v; v[0] = 0.f; v[1] = 0.f; v[2] = 0.f; v[3] = 0.f; return v;
}
// async global->LDS, 16B per lane; LDS dest = wave-uniform base + lane*16
static __device__ __forceinline__ void gload_lds16(const ushort_t* g, ushort_t* l) {
    __builtin_amdgcn_global_load_lds(
        (const __attribute__((address_space(1))) uint_t*)g,
        (__attribute__((address_space(3))) uint_t*)l, 16, 0, 0);
}

#define RP_LD 1216          // Rp rows per head: 64 zero-pad + 1025 valid + tail pad

// ---------------- zero fill (uint4 granularity) ----------------
__global__ __launch_bounds__(256) void zero_fill(uint4* __restrict__ p) {
    const size_t i = (size_t)blockIdx.x * 256 + threadIdx.x;
    p[i] = make_uint4(0u, 0u, 0u, 0u);
}

// ---------------- cast [w;r] -> bf16 A ----------------
__global__ __launch_bounds__(256) void cast_a(const float* __restrict__ w,
                                              const float* __restrict__ r,
                                              ushort_t* __restrict__ A) {
    const int row = blockIdx.x, t = threadIdx.x;
    float4 v = make_float4(0.f, 0.f, 0.f, 0.f);
    if (row < 4096)      v = *(const float4*)(w + (size_t)row * 1024 + t * 4);
    else if (row < 5121) v = *(const float4*)(r + (size_t)(row - 4096) * 1024 + t * 4);
    ushort4 o;
    o.x = f2bf(v.x); o.y = f2bf(v.y); o.z = f2bf(v.z); o.w = f2bf(v.w);
    *(ushort4*)(A + (size_t)row * 1024 + t * 4) = o;
}

// ---------------- transpose + cast: in f32 [R][C] -> out bf16 [C][R] ----------------
__global__ __launch_bounds__(256) void tcast(const float* __restrict__ in,
                                             ushort_t* __restrict__ out,
                                             int R, int C) {
    __shared__ float Ts[64][65];
    const int c0 = blockIdx.x * 64, r0 = blockIdx.y * 64, t = threadIdx.x;
#pragma unroll
    for (int rep = 0; rep < 4; ++rep) {
        const int idx = t + rep * 256;
        const int rr = idx >> 4, c4 = (idx & 15) * 4;
        *(float4*)&Ts[rr][c4] = *(const float4*)(in + (size_t)(r0 + rr) * C + c0 + c4);
    }
    __syncthreads();
#pragma unroll
    for (int rep = 0; rep < 2; ++rep) {
        const int idx = t + rep * 256;
        const int cc = idx >> 3, r8 = (idx & 7) * 8;
        alignas(16) ushort_t tmp[8];
#pragma unroll
        for (int e = 0; e < 8; ++e) tmp[e] = f2bf(Ts[r8 + e][cc]);
        *(uint4*)(out + (size_t)(c0 + cc) * R + r0 + r8) = *(const uint4*)tmp;
    }
}

// ---------------- rq[n] = r[1024] @ W_qkv[:, n] ----------------
__global__ __launch_bounds__(256) void rq_kernel(const float* __restrict__ r,
                                                 const float* __restrict__ Wqkv,
                                                 float* __restrict__ rq) {
    const int nb = blockIdx.x & 3, kb = blockIdx.x >> 2;
    const int n = nb * 256 + threadIdx.x;
    const float* rrow = r + (size_t)1024 * 1024;
    float s = 0.f;
    const int k0 = kb * 128;
    for (int k = k0; k < k0 + 128; ++k) s += rrow[k] * Wqkv[(size_t)k * 3072 + n];
    atomicAdd(rq + n, s);
}

// ---------------- GEMM1: A[5248][1024] @ Bqt[3072][1024]^T, fused epilogue ----------
// grid: 840 blocks 1-D.  y<32: x=0..23 (Q/K/V sections).  y>=32: x=8..15 (K sec -> R).
__global__ __launch_bounds__(256) void gemm_qkv(const ushort_t* __restrict__ A,
                                                const ushort_t* __restrict__ Bt,
                                                const float* __restrict__ rq,
                                                ushort_t* __restrict__ Qp,
                                                ushort_t* __restrict__ Kp,
                                                ushort_t* __restrict__ Vp,
                                                ushort_t* __restrict__ Rp) {
    // staging: As = smem[0..8191] as [128][64], Bs = smem[8192..16383] as [128][64]
    // epilogue reuse: up to 18432 ushort (pitch-72 panels)
    __shared__ alignas(16) ushort_t smem[18432];

    // bijective XCD swizzle (840 = 8 * 105), then 1-D -> (x, y) tile decode
    const uint_t bid0 = blockIdx.x;
    const uint_t bid = (bid0 & 7u) * 105u + (bid0 >> 3);
    int xt, yt;
    if (bid < 768u) { yt = bid / 24u; xt = bid % 24u; }
    else            { const uint_t k = bid - 768u; yt = 32 + k / 8u; xt = 8 + k % 8u; }

    const int n0 = xt * 128, m0 = yt * 128;
    const int t = threadIdx.x, w = t >> 6, l = t & 63;
    const int wm = w >> 1, wn = w & 1, lr = l & 15, lk = l >> 4;
    f32x4 acc[4][4];
#pragma unroll
    for (int i = 0; i < 4; ++i)
#pragma unroll
        for (int j = 0; j < 4; ++j) acc[i][j] = fzero();

    // per-lane staging source (wave w stages rows w*32..w*32+31 of each tile)
    const int srow = l >> 3, scol = (l & 7) * 8;
    const ushort_t* gA = A  + (size_t)(m0 + w * 32 + srow) * 1024 + scol;
    const ushort_t* gB = Bt + (size_t)(n0 + w * 32 + srow) * 1024 + scol;
    ushort_t* lA = &smem[(w * 32) * 64];
    ushort_t* lB = &smem[8192 + (w * 32) * 64];

    for (int kt = 0; kt < 16; ++kt) {
        __syncthreads();   // previous iteration's LDS reads done
#pragma unroll
        for (int q = 0; q < 4; ++q) {
            gload_lds16(gA + (size_t)q * 8192 + kt * 64, lA + q * 512);
            gload_lds16(gB + (size_t)q * 8192 + kt * 64, lB + q * 512);
        }
        __syncthreads();   // vmcnt(0) drain + visibility
#pragma unroll
        for (int kk = 0; kk < 2; ++kk) {
            bf16x8 a[4], b[4];
#pragma unroll
            for (int mb = 0; mb < 4; ++mb)
                a[mb] = *(const bf16x8*)&smem[(wm * 64 + mb * 16 + lr) * 64 + kk * 32 + lk * 8];
#pragma unroll
            for (int nb = 0; nb < 4; ++nb)
                b[nb] = *(const bf16x8*)&smem[8192 + (wn * 64 + nb * 16 + lr) * 64 + kk * 32 + lk * 8];
#pragma unroll
            for (int mb = 0; mb < 4; ++mb)
#pragma unroll
                for (int nb = 0; nb < 4; ++nb)
                    acc[mb][nb] = MFMA(a[mb], b[nb], acc[mb][nb]);
        }
    }

    const int sec = n0 >> 10;   // 0:Q 1:K 2:V (tile-uniform)
    float rqv[4];
    if (sec == 0) {
#pragma unroll
        for (int nb = 0; nb < 4; ++nb)
            rqv[nb] = rq[n0 + wn * 64 + nb * 16 + lr];
    }
    __syncthreads();   // all frag reads done before smem reuse

    if (m0 < 4096) {
        // Fragment layout: b = r2, nh_local = wn, i_loc = wm*16+mb*4+lk, d = nb*16+lr.
        // Stage 8 panels [b][nh][i(32)][d(64)] at pitch 72.
#pragma unroll
        for (int mb = 0; mb < 4; ++mb)
#pragma unroll
            for (int nb = 0; nb < 4; ++nb)
#pragma unroll
                for (int r2 = 0; r2 < 4; ++r2) {
                    float v = acc[mb][nb][r2];
                    if (sec == 0) v += rqv[nb];
                    smem[(r2 * 2 + wn) * 2304 + (wm * 16 + mb * 4 + lk) * 72 +
                         nb * 16 + lr] = f2bf(v);
                }
        __syncthreads();
        ushort_t* dst = (sec == 0) ? Qp : ((sec == 1) ? Kp : Vp);
        const int hbase = (n0 & 1023) >> 6;
        const int ibase = m0 >> 2;
#pragma unroll
        for (int rep = 0; rep < 8; ++rep) {
            const int f = rep * 256 + t;
            const int panel = f >> 8, il = (f >> 3) & 31, d8 = (f & 7) * 8;
            const int b = panel >> 1, nh = panel & 1;
            const uint4 v = *(const uint4*)&smem[panel * 2304 + il * 72 + d8];
            *(uint4*)(dst + ((size_t)(b * 16 + hbase + nh) * 1024 + ibase + il) * 64 + d8) = v;
        }
    } else {
        // R rows (sec==1 only reaches here): idx_local = wm*64+mb*16+lk*4+r2.
        // A rows >=5121 are zero, so tail writes are zeros (safe; zeros expected).
#pragma unroll
        for (int mb = 0; mb < 4; ++mb)
#pragma unroll
            for (int nb = 0; nb < 4; ++nb)
#pragma unroll
                for (int r2 = 0; r2 < 4; ++r2)
                    smem[wn * 9216 + (wm * 64 + mb * 16 + lk * 4 + r2) * 72 +
                         nb * 16 + lr] = f2bf(acc[mb][nb][r2]);
        __syncthreads();
        const int hbase = (n0 & 1023) >> 6;
        const int rbase0 = 64 + (m0 - 4096);
#pragma unroll
        for (int rep = 0; rep < 8; ++rep) {
            const int f = rep * 256 + t;
            const int nh = f >> 10, il = (f >> 3) & 127, d8 = (f & 7) * 8;
            const uint4 v = *(const uint4*)&smem[nh * 9216 + il * 72 + d8];
            *(uint4*)(Rp + ((size_t)(hbase + nh) * RP_LD + rbase0 + il) * 64 + d8) = v;
        }
    }
}

// ---------------- V transpose: Vp[(bn)][j][d] -> Vt[(bn)][d][j] ----------------
__global__ __launch_bounds__(256) void transpose_v(const ushort_t* __restrict__ Vp,
                                                   ushort_t* __restrict__ Vt) {
    __shared__ ushort_t Ts[64][72];
    const int j0 = blockIdx.x * 64, bn = blockIdx.y, t = threadIdx.x;
#pragma unroll
    for (int rep = 0; rep < 2; ++rep) {
        const int idx = t + rep * 256;
        const int jj = idx >> 3, c8 = (idx & 7) * 8;
        *(uint4*)&Ts[jj][c8] = *(const uint4*)(Vp + ((size_t)bn * 1024 + j0 + jj) * 64 + c8);
    }
    __syncthreads();
#pragma unroll
    for (int rep = 0; rep < 2; ++rep) {
        const int idx = t + rep * 256;
        const int d = idx >> 3, j8 = (idx & 7) * 8;
        alignas(16) ushort_t tmp[8];
#pragma unroll
        for (int e = 0; e < 8; ++e) tmp[e] = Ts[j8 + e][d];
        *(uint4*)(Vt + ((size_t)bn * 64 + d) * 1024 + j0 + j8) = *(const uint4*)tmp;
    }
}

// ---------------- flash attention with banded rel term ----------------
// grid (16 i-tiles reversed, 64 bn). 4 waves x 16 rows each.
__global__ __launch_bounds__(256) void attn(const ushort_t* __restrict__ Qp,
                                            const ushort_t* __restrict__ Kp,
                                            const ushort_t* __restrict__ Vt,
                                            const ushort_t* __restrict__ Rp,
                                            ushort_t* __restrict__ av) {
    __shared__ alignas(16) ushort_t Ks [64][72];
    __shared__ alignas(16) ushort_t Vts[64][72];
    __shared__ alignas(16) ushort_t Pl [64][72];
    __shared__ alignas(16) ushort_t Rs [128][72];
    __shared__ alignas(16) ushort_t Dl [64][136];

    const int it = 15 - blockIdx.x, i0 = it * 64;
    const int bn = blockIdx.y, b = bn >> 4, n = bn & 15;
    const int t = threadIdx.x, w = t >> 6, l = t & 63, lr = l & 15, lk = l >> 4;

    // Q' fragments straight from global (row-major per (b,n))
    bf16x8 qf0, qf1;
    {
        const ushort_t* qb = Qp + ((size_t)bn * 1024 + i0 + w * 16 + lr) * 64 + lk * 8;
        qf0 = *(const bf16x8*)qb;
        qf1 = *(const bf16x8*)(qb + 32);
    }

    f32x4 O[4];
#pragma unroll
    for (int db = 0; db < 4; ++db) O[db] = fzero();
    float mrun[4] = {-INFINITY, -INFINITY, -INFINITY, -INFINITY};
    float lrun[4] = {0.f, 0.f, 0.f, 0.f};

    for (int jt = 0; jt <= it; ++jt) {
        const int j0 = jt * 64;
        const int rbase = 1025 + j0 - i0;   // Rp row (incl +64 pad shift) for band col 0
        // stage K (64 rows), Vt (64 rows), R band (128 rows); 128B per row
#pragma unroll
        for (int rep = 0; rep < 8; ++rep) {
            const int idx = t + rep * 256;
            const int rr = idx >> 3, c8 = (idx & 7) * 8;
            if (rr < 64) {
                *(uint4*)&Ks[rr][c8] =
                    *(const uint4*)(Kp + ((size_t)bn * 1024 + j0 + rr) * 64 + c8);
            } else if (rr < 128) {
                *(uint4*)&Vts[rr - 64][c8] =
                    *(const uint4*)(Vt + ((size_t)bn * 64 + (rr - 64)) * 1024 + j0 + c8);
            } else {
                *(uint4*)&Rs[rr - 128][c8] =
                    *(const uint4*)(Rp + ((size_t)n * RP_LD + rbase + (rr - 128)) * 64 + c8);
            }
        }
        __syncthreads();

        // banded rel term: wave w needs band cols [48-16w, 127-16w] -> 5 col-blocks
#pragma unroll
        for (int q5 = 0; q5 < 5; ++q5) {
            const int cb2 = (3 - w) + q5;
            f32x4 d = fzero();
            bf16x8 rb0 = *(const bf16x8*)&Rs[cb2 * 16 + lr][lk * 8];
            bf16x8 rb1 = *(const bf16x8*)&Rs[cb2 * 16 + lr][32 + lk * 8];
            d = MFMA(qf0, rb0, d);
            d = MFMA(qf1, rb1, d);
#pragma unroll
            for (int r2 = 0; r2 < 4; ++r2)
                Dl[w * 16 + lk * 4 + r2][cb2 * 16 + lr] = f2bf(d[r2]);
        }

        // ac = Q'.K^T
        float sv[4][4];
#pragma unroll
        for (int cb = 0; cb < 4; ++cb) {
            f32x4 s = fzero();
            bf16x8 kb0 = *(const bf16x8*)&Ks[cb * 16 + lr][lk * 8];
            bf16x8 kb1 = *(const bf16x8*)&Ks[cb * 16 + lr][32 + lk * 8];
            s = MFMA(qf0, kb0, s);
            s = MFMA(qf1, kb1, s);
#pragma unroll
            for (int r2 = 0; r2 < 4; ++r2) sv[cb][r2] = s[r2];
        }

        // assemble: add shifted band, scale, causal mask
#pragma unroll
        for (int r2 = 0; r2 < 4; ++r2) {
            const int ii = w * 16 + lk * 4 + r2;
            const int gi = i0 + ii;
#pragma unroll
            for (int cb = 0; cb < 4; ++cb) {
                const int jj = cb * 16 + lr;
                const float v = sv[cb][r2] + bf2f(Dl[ii][jj - ii + 63]);
                sv[cb][r2] = (j0 + jj > gi) ? -3.0e38f : v * 0.125f;
            }
        }

        // online softmax (16-lane groups hold a full row)
#pragma unroll
        for (int r2 = 0; r2 < 4; ++r2) {
            float tmax = fmaxf(fmaxf(sv[0][r2], sv[1][r2]), fmaxf(sv[2][r2], sv[3][r2]));
            tmax = fmaxf(tmax, __shfl_xor(tmax, 1));
            tmax = fmaxf(tmax, __shfl_xor(tmax, 2));
            tmax = fmaxf(tmax, __shfl_xor(tmax, 4));
            tmax = fmaxf(tmax, __shfl_xor(tmax, 8));
            const float mnew = fmaxf(mrun[r2], tmax);
            const float corr = __expf(mrun[r2] - mnew);
            mrun[r2] = mnew;
            float psum = 0.f;
#pragma unroll
            for (int cb = 0; cb < 4; ++cb) {
                const float p = __expf(sv[cb][r2] - mnew);
                sv[cb][r2] = p;
                psum += p;
            }
            psum += __shfl_xor(psum, 1);
            psum += __shfl_xor(psum, 2);
            psum += __shfl_xor(psum, 4);
            psum += __shfl_xor(psum, 8);
            lrun[r2] = lrun[r2] * corr + psum;
#pragma unroll
            for (int db = 0; db < 4; ++db) O[db][r2] *= corr;
#pragma unroll
            for (int cb = 0; cb < 4; ++cb)
                Pl[w * 16 + lk * 4 + r2][cb * 16 + lr] = f2bf(sv[cb][r2]);
        }

        // PV: O += P @ V   (A-frag from Pl rows, B-frag from V^T rows)
        bf16x8 pa0 = *(const bf16x8*)&Pl[w * 16 + lr][lk * 8];
        bf16x8 pa1 = *(const bf16x8*)&Pl[w * 16 + lr][32 + lk * 8];
#pragma unroll
        for (int db = 0; db < 4; ++db) {
            bf16x8 vb0 = *(const bf16x8*)&Vts[db * 16 + lr][lk * 8];
            bf16x8 vb1 = *(const bf16x8*)&Vts[db * 16 + lr][32 + lk * 8];
            O[db] = MFMA(pa0, vb0, O[db]);
            O[db] = MFMA(pa1, vb1, O[db]);
        }
        __syncthreads();
    }

#pragma unroll
    for (int r2 = 0; r2 < 4; ++r2) {
        const float inv = 1.0f / lrun[r2];
        const int row = (i0 + w * 16 + lk * 4 + r2) * 4 + b;
#pragma unroll
        for (int db = 0; db < 4; ++db)
            av[(size_t)row * 1024 + n * 64 + db * 16 + lr] = f2bf(O[db][r2] * inv);
    }
}

// ---------------- GEMM-O: av[4096][1024] @ Bot[1024][1024]^T -> f32 ----------------
__global__ __launch_bounds__(256) void gemm_o(const ushort_t* __restrict__ A,
                                              const ushort_t* __restrict__ Bt,
                                              float* __restrict__ C) {
    __shared__ alignas(16) ushort_t smem[16384];   // As[128][64] | Bs[128][64]
    const int n0 = blockIdx.x * 128, m0 = blockIdx.y * 128;
    const int t = threadIdx.x, w = t >> 6, l = t & 63;
    const int wm = w >> 1, wn = w & 1, lr = l & 15, lk = l >> 4;
    f32x4 acc[4][4];
#pragma unroll
    for (int i = 0; i < 4; ++i)
#pragma unroll
        for (int j = 0; j < 4; ++j) acc[i][j] = fzero();

    const int srow = l >> 3, scol = (l & 7) * 8;
    const ushort_t* gA = A  + (size_t)(m0 + w * 32 + srow) * 1024 + scol;
    const ushort_t* gB = Bt + (size_t)(n0 + w * 32 + srow) * 1024 + scol;
    ushort_t* lA = &smem[(w * 32) * 64];
    ushort_t* lB = &smem[8192 + (w * 32) * 64];

    for (int kt = 0; kt < 16; ++kt) {
        __syncthreads();
#pragma unroll
        for (int q = 0; q < 4; ++q) {
            gload_lds16(gA + (size_t)q * 8192 + kt * 64, lA + q * 512);
            gload_lds16(gB + (size_t)q * 8192 + kt * 64, lB + q * 512);
        }
        __syncthreads();
#pragma unroll
        for (int kk = 0; kk < 2; ++kk) {
            bf16x8 a[4], b[4];
#pragma unroll
            for (int mb = 0; mb < 4; ++mb)
                a[mb] = *(const bf16x8*)&smem[(wm * 64 + mb * 16 + lr) * 64 + kk * 32 + lk * 8];
#pragma unroll
            for (int nb = 0; nb < 4; ++nb)
                b[nb] = *(const bf16x8*)&smem[8192 + (wn * 64 + nb * 16 + lr) * 64 + kk * 32 + lk * 8];
#pragma unroll
            for (int mb = 0; mb < 4; ++mb)
#pragma unroll
                for (int nb = 0; nb < 4; ++nb)
                    acc[mb][nb] = MFMA(a[mb], b[nb], acc[mb][nb]);
        }
    }
#pragma unroll
    for (int mb = 0; mb < 4; ++mb)
#pragma unroll
        for (int nb = 0; nb < 4; ++nb)
#pragma unroll
            for (int r2 = 0; r2 < 4; ++r2)
                C[(size_t)(m0 + wm * 64 + mb * 16 + lk * 4 + r2) * 1024 +
                  n0 + wn * 64 + nb * 16 + lr] = acc[mb][nb][r2];
}

// ---------------- Residual + LayerNorm ----------------
__global__ __launch_bounds__(256) void ln_kernel(const float* __restrict__ w,
                                                 const float* __restrict__ ao,
                                                 const float* __restrict__ gamma,
                                                 const float* __restrict__ beta,
                                                 float* __restrict__ out) {
    const int row = blockIdx.x;
    const int t = threadIdx.x;
    const size_t base = (size_t)row * 1024 + t * 4;
    const float4 xw = *(const float4*)(w + base);
    const float4 xa = *(const float4*)(ao + base);
    float x[4] = { xw.x + xa.x, xw.y + xa.y, xw.z + xa.z, xw.w + xa.w };
    float sum = x[0] + x[1] + x[2] + x[3];
    float sq  = x[0]*x[0] + x[1]*x[1] + x[2]*x[2] + x[3]*x[3];
#pragma unroll
    for (int off = 1; off < 64; off <<= 1) {
        sum += __shfl_xor(sum, off);
        sq  += __shfl_xor(sq, off);
    }
    __shared__ float ssum[4], ssq[4];
    const int wid = t >> 6;
    if ((t & 63) == 0) { ssum[wid] = sum; ssq[wid] = sq; }
    __syncthreads();
    sum = ssum[0] + ssum[1] + ssum[2] + ssum[3];
    sq  = ssq[0] + ssq[1] + ssq[2] + ssq[3];
    const float mu   = sum * (1.f / 1024.f);
    const float var  = sq * (1.f / 1024.f) - mu * mu;
    const float rstd = rsqrtf(var + 1e-5f);
    const float4 g4 = *(const float4*)(gamma + t * 4);
    const float4 b4 = *(const float4*)(beta + t * 4);
    float4 o;
    o.x = (x[0] - mu) * rstd * g4.x + b4.x;
    o.y = (x[1] - mu) * rstd * g4.y + b4.y;
    o.z = (x[2] - mu) * rstd * g4.z + b4.z;
    o.w = (x[3] - mu) * rstd * g4.w + b4.w;
    *(float4*)(out + base) = o;
}

extern "C" void kernel_launch(void* const* d_in, const int* in_sizes, int n_in,
                              void* d_out, int out_size, void* d_ws, size_t ws_size,
                              hipStream_t stream) {
    const float* w     = (const float*)d_in[0];
    const float* r     = (const float*)d_in[1];
    // d_in[2] attn_mask: deterministic causal mask, computed inline
    const float* Wqkv  = (const float*)d_in[3];
    const float* Wo    = (const float*)d_in[4];
    const float* gamma = (const float*)d_in[5];
    const float* beta  = (const float*)d_in[6];
    float* out = (float*)d_out;

    char* base = (char*)d_ws;
    ushort_t* A16  = (ushort_t*)(base + 0);           // [5248][1024]
    ushort_t* Bqt  = (ushort_t*)(base + 10747904);    // [3072][1024]
    ushort_t* Bot  = (ushort_t*)(base + 17039360);    // [1024][1024]
    ushort_t* Qp   = (ushort_t*)(base + 19136512);    // [(b,n)][1024][64]
    ushort_t* Kp   = (ushort_t*)(base + 27525120);
    ushort_t* Vp   = (ushort_t*)(base + 35913728);
    ushort_t* Vtp  = (ushort_t*)(base + 44302336);    // [(b,n)][64][1024]
    ushort_t* Rp   = (ushort_t*)(base + 52690944);    // [16][1216][64]
    float*    rq   = (float*)   (base + 55181312);    // [1024]
    ushort_t* av   = (ushort_t*)(base + 55185408);    // [4096][1024]
    float*    wsao = (float*)   (base + 63574016);    // [4096][1024]

    // zero Rp (incl. pads) + rq: 2490368 + 4096 bytes = 155904 uint4
    zero_fill<<<609, 256, 0, stream>>>((uint4*)Rp);
    cast_a<<<5248, 256, 0, stream>>>(w, r, A16);
    tcast<<<dim3(48, 16), 256, 0, stream>>>(Wqkv, Bqt, 1024, 3072);
    tcast<<<dim3(16, 16), 256, 0, stream>>>(Wo, Bot, 1024, 1024);
    rq_kernel<<<32, 256, 0, stream>>>(r, Wqkv, rq);
    gemm_qkv<<<840, 256, 0, stream>>>(A16, Bqt, rq, Qp, Kp, Vp, Rp);
    transpose_v<<<dim3(16, 64), 256, 0, stream>>>(Vp, Vtp);
    attn<<<dim3(16, 64), 256, 0, stream>>>(Qp, Kp, Vtp, Rp, av);
    gemm_o<<<dim3(8, 32), 256, 0, stream>>>(av, Bot, wsao);
    ln_kernel<<<4096, 256, 0, stream>>>(w, wsao, gamma, beta, out);
}

// Round 8
// 325.843 us; speedup vs baseline: 6.5600x; 1.0613x over previous
//
#include <hip/hip_runtime.h>
#include <hip/hip_bf16.h>
#include <math.h>

// Transformer-XL RelMultiHeadAttn — bf16 MFMA pipeline.
// QLEN=1024 BSZ=4 DMODEL=1024 NHEAD=16 DHEAD=64 RLEN=1025
// score(i,j) = Q'_i.(K_j) + Q'_i.R_{1024+j-i} (rel-shift closed form), j<=i.
//
// R8 changes (attn only): barrier-free rewrite.
//  - K/V/R fragments read DIRECTLY from global (L2-resident: 256KB K+V per bn;
//    XCD swizzle keeps all blocks of one bn on one XCD). No LDS staging.
//  - Dl/Pl are wave-private LDS (26.6 KB/block, was 62 KB) -> no __syncthreads.
//  - i-tile pairing (16-x)+(x+1)=17 iters/block: perfect load balance, 512 blocks.
//  - exp2-domain softmax (scale folds 0.125*log2e); mask only on diagonal tile.

typedef short bf16x8 __attribute__((ext_vector_type(8)));
typedef float f32x4  __attribute__((ext_vector_type(4)));
typedef unsigned short ushort_t;
typedef unsigned int uint_t;

#define MFMA(a, b, c) __builtin_amdgcn_mfma_f32_16x16x32_bf16((a), (b), (c), 0, 0, 0)

static __device__ __forceinline__ ushort_t f2bf(float f) {
    uint_t x = __float_as_uint(f);
    uint_t r = (x + 0x7fffu + ((x >> 16) & 1u)) >> 16;   // RTNE
    return (ushort_t)r;
}
static __device__ __forceinline__ float bf2f(ushort_t u) {
    return __uint_as_float(((uint_t)u) << 16);
}
static __device__ __forceinline__ f32x4 fzero() {
    f32x4 v; v[0] = 0.f; v[1] = 0.f; v[2] = 0.f; v[3] = 0.f; return v;
}
// async global->LDS, 16B per lane; LDS dest = wave-uniform base + lane*16
static __device__ __forceinline__ void gload_lds16(const ushort_t* g, ushort_t* l) {
    __builtin_amdgcn_global_load_lds(
        (const __attribute__((address_space(1))) uint_t*)g,
        (__attribute__((address_space(3))) uint_t*)l, 16, 0, 0);
}

#define RP_LD 1216          // Rp rows per head: 64 zero-pad + 1025 valid + tail pad

// ---------------- zero fill (uint4 granularity) ----------------
__global__ __launch_bounds__(256) void zero_fill(uint4* __restrict__ p) {
    const size_t i = (size_t)blockIdx.x * 256 + threadIdx.x;
    p[i] = make_uint4(0u, 0u, 0u, 0u);
}

// ---------------- cast [w;r] -> bf16 A ----------------
__global__ __launch_bounds__(256) void cast_a(const float* __restrict__ w,
                                              const float* __restrict__ r,
                                              ushort_t* __restrict__ A) {
    const int row = blockIdx.x, t = threadIdx.x;
    float4 v = make_float4(0.f, 0.f, 0.f, 0.f);
    if (row < 4096)      v = *(const float4*)(w + (size_t)row * 1024 + t * 4);
    else if (row < 5121) v = *(const float4*)(r + (size_t)(row - 4096) * 1024 + t * 4);
    ushort4 o;
    o.x = f2bf(v.x); o.y = f2bf(v.y); o.z = f2bf(v.z); o.w = f2bf(v.w);
    *(ushort4*)(A + (size_t)row * 1024 + t * 4) = o;
}

// ---------------- transpose + cast: in f32 [R][C] -> out bf16 [C][R] ----------------
__global__ __launch_bounds__(256) void tcast(const float* __restrict__ in,
                                             ushort_t* __restrict__ out,
                                             int R, int C) {
    __shared__ float Ts[64][65];
    const int c0 = blockIdx.x * 64, r0 = blockIdx.y * 64, t = threadIdx.x;
#pragma unroll
    for (int rep = 0; rep < 4; ++rep) {
        const int idx = t + rep * 256;
        const int rr = idx >> 4, c4 = (idx & 15) * 4;
        *(float4*)&Ts[rr][c4] = *(const float4*)(in + (size_t)(r0 + rr) * C + c0 + c4);
    }
    __syncthreads();
#pragma unroll
    for (int rep = 0; rep < 2; ++rep) {
        const int idx = t + rep * 256;
        const int cc = idx >> 3, r8 = (idx & 7) * 8;
        alignas(16) ushort_t tmp[8];
#pragma unroll
        for (int e = 0; e < 8; ++e) tmp[e] = f2bf(Ts[r8 + e][cc]);
        *(uint4*)(out + (size_t)(c0 + cc) * R + r0 + r8) = *(const uint4*)tmp;
    }
}

// ---------------- rq[n] = r[1024] @ W_qkv[:, n] ----------------
__global__ __launch_bounds__(256) void rq_kernel(const float* __restrict__ r,
                                                 const float* __restrict__ Wqkv,
                                                 float* __restrict__ rq) {
    const int nb = blockIdx.x & 3, kb = blockIdx.x >> 2;
    const int n = nb * 256 + threadIdx.x;
    const float* rrow = r + (size_t)1024 * 1024;
    float s = 0.f;
    const int k0 = kb * 128;
    for (int k = k0; k < k0 + 128; ++k) s += rrow[k] * Wqkv[(size_t)k * 3072 + n];
    atomicAdd(rq + n, s);
}

// ---------------- GEMM1: A[5248][1024] @ Bqt[3072][1024]^T, fused epilogue ----------
// grid: 840 blocks 1-D.  y<32: x=0..23 (Q/K/V sections).  y>=32: x=8..15 (K sec -> R).
__global__ __launch_bounds__(256) void gemm_qkv(const ushort_t* __restrict__ A,
                                                const ushort_t* __restrict__ Bt,
                                                const float* __restrict__ rq,
                                                ushort_t* __restrict__ Qp,
                                                ushort_t* __restrict__ Kp,
                                                ushort_t* __restrict__ Vp,
                                                ushort_t* __restrict__ Rp) {
    // staging: As = smem[0..8191] as [128][64], Bs = smem[8192..16383] as [128][64]
    // epilogue reuse: up to 18432 ushort (pitch-72 panels)
    __shared__ alignas(16) ushort_t smem[18432];

    // bijective XCD swizzle (840 = 8 * 105), then 1-D -> (x, y) tile decode
    const uint_t bid0 = blockIdx.x;
    const uint_t bid = (bid0 & 7u) * 105u + (bid0 >> 3);
    int xt, yt;
    if (bid < 768u) { yt = bid / 24u; xt = bid % 24u; }
    else            { const uint_t k = bid - 768u; yt = 32 + k / 8u; xt = 8 + k % 8u; }

    const int n0 = xt * 128, m0 = yt * 128;
    const int t = threadIdx.x, w = t >> 6, l = t & 63;
    const int wm = w >> 1, wn = w & 1, lr = l & 15, lk = l >> 4;
    f32x4 acc[4][4];
#pragma unroll
    for (int i = 0; i < 4; ++i)
#pragma unroll
        for (int j = 0; j < 4; ++j) acc[i][j] = fzero();

    // per-lane staging source (wave w stages rows w*32..w*32+31 of each tile)
    const int srow = l >> 3, scol = (l & 7) * 8;
    const ushort_t* gA = A  + (size_t)(m0 + w * 32 + srow) * 1024 + scol;
    const ushort_t* gB = Bt + (size_t)(n0 + w * 32 + srow) * 1024 + scol;
    ushort_t* lA = &smem[(w * 32) * 64];
    ushort_t* lB = &smem[8192 + (w * 32) * 64];

    for (int kt = 0; kt < 16; ++kt) {
        __syncthreads();   // previous iteration's LDS reads done
#pragma unroll
        for (int q = 0; q < 4; ++q) {
            gload_lds16(gA + (size_t)q * 8192 + kt * 64, lA + q * 512);
            gload_lds16(gB + (size_t)q * 8192 + kt * 64, lB + q * 512);
        }
        __syncthreads();   // vmcnt(0) drain + visibility
#pragma unroll
        for (int kk = 0; kk < 2; ++kk) {
            bf16x8 a[4], b[4];
#pragma unroll
            for (int mb = 0; mb < 4; ++mb)
                a[mb] = *(const bf16x8*)&smem[(wm * 64 + mb * 16 + lr) * 64 + kk * 32 + lk * 8];
#pragma unroll
            for (int nb = 0; nb < 4; ++nb)
                b[nb] = *(const bf16x8*)&smem[8192 + (wn * 64 + nb * 16 + lr) * 64 + kk * 32 + lk * 8];
#pragma unroll
            for (int mb = 0; mb < 4; ++mb)
#pragma unroll
                for (int nb = 0; nb < 4; ++nb)
                    acc[mb][nb] = MFMA(a[mb], b[nb], acc[mb][nb]);
        }
    }

    const int sec = n0 >> 10;   // 0:Q 1:K 2:V (tile-uniform)
    float rqv[4];
    if (sec == 0) {
#pragma unroll
        for (int nb = 0; nb < 4; ++nb)
            rqv[nb] = rq[n0 + wn * 64 + nb * 16 + lr];
    }
    __syncthreads();   // all frag reads done before smem reuse

    if (m0 < 4096) {
        // Fragment layout: b = r2, nh_local = wn, i_loc = wm*16+mb*4+lk, d = nb*16+lr.
        // Stage 8 panels [b][nh][i(32)][d(64)] at pitch 72.
#pragma unroll
        for (int mb = 0; mb < 4; ++mb)
#pragma unroll
            for (int nb = 0; nb < 4; ++nb)
#pragma unroll
                for (int r2 = 0; r2 < 4; ++r2) {
                    float v = acc[mb][nb][r2];
                    if (sec == 0) v += rqv[nb];
                    smem[(r2 * 2 + wn) * 2304 + (wm * 16 + mb * 4 + lk) * 72 +
                         nb * 16 + lr] = f2bf(v);
                }
        __syncthreads();
        ushort_t* dst = (sec == 0) ? Qp : ((sec == 1) ? Kp : Vp);
        const int hbase = (n0 & 1023) >> 6;
        const int ibase = m0 >> 2;
#pragma unroll
        for (int rep = 0; rep < 8; ++rep) {
            const int f = rep * 256 + t;
            const int panel = f >> 8, il = (f >> 3) & 31, d8 = (f & 7) * 8;
            const int b = panel >> 1, nh = panel & 1;
            const uint4 v = *(const uint4*)&smem[panel * 2304 + il * 72 + d8];
            *(uint4*)(dst + ((size_t)(b * 16 + hbase + nh) * 1024 + ibase + il) * 64 + d8) = v;
        }
    } else {
        // R rows (sec==1 only reaches here): idx_local = wm*64+mb*16+lk*4+r2.
        // A rows >=5121 are zero, so tail writes are zeros (safe; zeros expected).
#pragma unroll
        for (int mb = 0; mb < 4; ++mb)
#pragma unroll
            for (int nb = 0; nb < 4; ++nb)
#pragma unroll
                for (int r2 = 0; r2 < 4; ++r2)
                    smem[wn * 9216 + (wm * 64 + mb * 16 + lk * 4 + r2) * 72 +
                         nb * 16 + lr] = f2bf(acc[mb][nb][r2]);
        __syncthreads();
        const int hbase = (n0 & 1023) >> 6;
        const int rbase0 = 64 + (m0 - 4096);
#pragma unroll
        for (int rep = 0; rep < 8; ++rep) {
            const int f = rep * 256 + t;
            const int nh = f >> 10, il = (f >> 3) & 127, d8 = (f & 7) * 8;
            const uint4 v = *(const uint4*)&smem[nh * 9216 + il * 72 + d8];
            *(uint4*)(Rp + ((size_t)(hbase + nh) * RP_LD + rbase0 + il) * 64 + d8) = v;
        }
    }
}

// ---------------- V transpose: Vp[(bn)][j][d] -> Vt[(bn)][d][j] ----------------
__global__ __launch_bounds__(256) void transpose_v(const ushort_t* __restrict__ Vp,
                                                   ushort_t* __restrict__ Vt) {
    __shared__ ushort_t Ts[64][72];
    const int j0 = blockIdx.x * 64, bn = blockIdx.y, t = threadIdx.x;
#pragma unroll
    for (int rep = 0; rep < 2; ++rep) {
        const int idx = t + rep * 256;
        const int jj = idx >> 3, c8 = (idx & 7) * 8;
        *(uint4*)&Ts[jj][c8] = *(const uint4*)(Vp + ((size_t)bn * 1024 + j0 + jj) * 64 + c8);
    }
    __syncthreads();
#pragma unroll
    for (int rep = 0; rep < 2; ++rep) {
        const int idx = t + rep * 256;
        const int d = idx >> 3, j8 = (idx & 7) * 8;
        alignas(16) ushort_t tmp[8];
#pragma unroll
        for (int e = 0; e < 8; ++e) tmp[e] = Ts[j8 + e][d];
        *(uint4*)(Vt + ((size_t)bn * 64 + d) * 1024 + j0 + j8) = *(const uint4*)tmp;
    }
}

// ---------------- flash attention, barrier-free ----------------
// grid: 512 blocks 1-D (XCD-swizzled by bn&7). 256 threads = 4 independent waves.
// Block handles i-tile pair {15-x, x}: 17 jt-iterations total (balanced).
// Wave w owns rows w*16..w*16+15 of each i-tile; K/V^T/R frags direct from L2.
__global__ __launch_bounds__(256) void attn(const ushort_t* __restrict__ Qp,
                                            const ushort_t* __restrict__ Kp,
                                            const ushort_t* __restrict__ Vt,
                                            const ushort_t* __restrict__ Rp,
                                            ushort_t* __restrict__ av) {
    __shared__ ushort_t DlS[4][2176];   // per-wave band buffer [16][136] bf16
    __shared__ ushort_t PlS[4][1152];   // per-wave P buffer    [16][72]  bf16

    const uint_t bid = blockIdx.x;
    const int bnl = bid & 7;             // XCD selector = bn & 7
    const uint_t rest = bid >> 3;        // 0..63
    const int xp = rest & 7;             // i-tile pair index 0..7
    const int bnh = rest >> 3;           // 0..7
    const int bn = bnh * 8 + bnl;
    const int b = bn >> 4, n = bn & 15;
    const int t = threadIdx.x, w = t >> 6, l = t & 63, lr = l & 15, lk = l >> 4;
    const int row4 = lk * 4;

    const ushort_t* Kb = Kp + (size_t)bn * 65536;
    const ushort_t* Vb = Vt + (size_t)bn * 65536;
    const ushort_t* Rb = Rp + (size_t)n * RP_LD * 64;
    const ushort_t* Qb = Qp + (size_t)bn * 65536;
    ushort_t* Dw = DlS[w];
    ushort_t* Pw = PlS[w];

    const float SCL = 0.18033688f;       // 0.125 * log2(e): exp2-domain softmax

#pragma unroll 1
    for (int ph = 0; ph < 2; ++ph) {
        const int it = ph ? xp : 15 - xp;
        const int i0 = it * 64;

        const ushort_t* qb = Qb + (size_t)(i0 + w * 16 + lr) * 64 + lk * 8;
        const bf16x8 qf0 = *(const bf16x8*)qb;
        const bf16x8 qf1 = *(const bf16x8*)(qb + 32);

        f32x4 O[4];
#pragma unroll
        for (int db = 0; db < 4; ++db) O[db] = fzero();
        float mrun[4] = {-INFINITY, -INFINITY, -INFINITY, -INFINITY};
        float lrun[4] = {0.f, 0.f, 0.f, 0.f};

        for (int jt = 0; jt <= it; ++jt) {
            const int j0 = jt * 64;
            const int rbase = 1025 + j0 - i0;

            // rel band: wave w needs band cols [48-16w, 128-16w) -> 5 col-blocks
#pragma unroll
            for (int q5 = 0; q5 < 5; ++q5) {
                const int cb2 = (3 - w) + q5;
                const ushort_t* rp = Rb + (size_t)(rbase + cb2 * 16 + lr) * 64 + lk * 8;
                f32x4 d = fzero();
                d = MFMA(qf0, *(const bf16x8*)rp, d);
                d = MFMA(qf1, *(const bf16x8*)(rp + 32), d);
#pragma unroll
                for (int r2 = 0; r2 < 4; ++r2)
                    Dw[(row4 + r2) * 136 + cb2 * 16 + lr] = f2bf(d[r2]);
            }

            // ac = Q'.K^T (frags straight from L2)
            float sv[4][4];
#pragma unroll
            for (int cb = 0; cb < 4; ++cb) {
                const ushort_t* kp = Kb + (size_t)(j0 + cb * 16 + lr) * 64 + lk * 8;
                f32x4 s = fzero();
                s = MFMA(qf0, *(const bf16x8*)kp, s);
                s = MFMA(qf1, *(const bf16x8*)(kp + 32), s);
#pragma unroll
                for (int r2 = 0; r2 < 4; ++r2) sv[cb][r2] = s[r2];
            }

            // assemble: add shifted band, scale (exp2 domain), diag-tile mask
            const bool diag = (jt == it);
#pragma unroll
            for (int r2 = 0; r2 < 4; ++r2) {
                const int rl = row4 + r2;
                const int ii = w * 16 + rl;
#pragma unroll
                for (int cb = 0; cb < 4; ++cb) {
                    const int jj = cb * 16 + lr;
                    float v = (sv[cb][r2] + bf2f(Dw[rl * 136 + jj - ii + 63])) * SCL;
                    sv[cb][r2] = (diag && jj > ii) ? -1.0e38f : v;
                }
            }

            // online softmax (16-lane groups hold a full row), base-2
#pragma unroll
            for (int r2 = 0; r2 < 4; ++r2) {
                float tmax = fmaxf(fmaxf(sv[0][r2], sv[1][r2]),
                                   fmaxf(sv[2][r2], sv[3][r2]));
                tmax = fmaxf(tmax, __shfl_xor(tmax, 1));
                tmax = fmaxf(tmax, __shfl_xor(tmax, 2));
                tmax = fmaxf(tmax, __shfl_xor(tmax, 4));
                tmax = fmaxf(tmax, __shfl_xor(tmax, 8));
                const float mnew = fmaxf(mrun[r2], tmax);
                const float corr = exp2f(mrun[r2] - mnew);
                mrun[r2] = mnew;
                float psum = 0.f;
#pragma unroll
                for (int cb = 0; cb < 4; ++cb) {
                    const float p = exp2f(sv[cb][r2] - mnew);
                    sv[cb][r2] = p;
                    psum += p;
                }
                psum += __shfl_xor(psum, 1);
                psum += __shfl_xor(psum, 2);
                psum += __shfl_xor(psum, 4);
                psum += __shfl_xor(psum, 8);
                lrun[r2] = lrun[r2] * corr + psum;
#pragma unroll
                for (int db = 0; db < 4; ++db) O[db][r2] *= corr;
#pragma unroll
                for (int cb = 0; cb < 4; ++cb)
                    Pw[(row4 + r2) * 72 + cb * 16 + lr] = f2bf(sv[cb][r2]);
            }

            // PV: O += P @ V  (A-frag from per-wave Pl, B-frag from V^T in L2)
            const bf16x8 pa0 = *(const bf16x8*)&Pw[lr * 72 + lk * 8];
            const bf16x8 pa1 = *(const bf16x8*)&Pw[lr * 72 + 32 + lk * 8];
#pragma unroll
            for (int db = 0; db < 4; ++db) {
                const ushort_t* vp = Vb + (size_t)(db * 16 + lr) * 1024 + j0 + lk * 8;
                O[db] = MFMA(pa0, *(const bf16x8*)vp, O[db]);
                O[db] = MFMA(pa1, *(const bf16x8*)(vp + 32), O[db]);
            }
        }

#pragma unroll
        for (int r2 = 0; r2 < 4; ++r2) {
            const float inv = 1.0f / lrun[r2];
            const int row = (i0 + w * 16 + row4 + r2) * 4 + b;
#pragma unroll
            for (int db = 0; db < 4; ++db)
                av[(size_t)row * 1024 + n * 64 + db * 16 + lr] = f2bf(O[db][r2] * inv);
        }
    }
}

// ---------------- GEMM-O: av[4096][1024] @ Bot[1024][1024]^T -> f32 ----------------
__global__ __launch_bounds__(256) void gemm_o(const ushort_t* __restrict__ A,
                                              const ushort_t* __restrict__ Bt,
                                              float* __restrict__ C) {
    __shared__ alignas(16) ushort_t smem[16384];   // As[128][64] | Bs[128][64]
    const int n0 = blockIdx.x * 128, m0 = blockIdx.y * 128;
    const int t = threadIdx.x, w = t >> 6, l = t & 63;
    const int wm = w >> 1, wn = w & 1, lr = l & 15, lk = l >> 4;
    f32x4 acc[4][4];
#pragma unroll
    for (int i = 0; i < 4; ++i)
#pragma unroll
        for (int j = 0; j < 4; ++j) acc[i][j] = fzero();

    const int srow = l >> 3, scol = (l & 7) * 8;
    const ushort_t* gA = A  + (size_t)(m0 + w * 32 + srow) * 1024 + scol;
    const ushort_t* gB = Bt + (size_t)(n0 + w * 32 + srow) * 1024 + scol;
    ushort_t* lA = &smem[(w * 32) * 64];
    ushort_t* lB = &smem[8192 + (w * 32) * 64];

    for (int kt = 0; kt < 16; ++kt) {
        __syncthreads();
#pragma unroll
        for (int q = 0; q < 4; ++q) {
            gload_lds16(gA + (size_t)q * 8192 + kt * 64, lA + q * 512);
            gload_lds16(gB + (size_t)q * 8192 + kt * 64, lB + q * 512);
        }
        __syncthreads();
#pragma unroll
        for (int kk = 0; kk < 2; ++kk) {
            bf16x8 a[4], b[4];
#pragma unroll
            for (int mb = 0; mb < 4; ++mb)
                a[mb] = *(const bf16x8*)&smem[(wm * 64 + mb * 16 + lr) * 64 + kk * 32 + lk * 8];
#pragma unroll
            for (int nb = 0; nb < 4; ++nb)
                b[nb] = *(const bf16x8*)&smem[8192 + (wn * 64 + nb * 16 + lr) * 64 + kk * 32 + lk * 8];
#pragma unroll
            for (int mb = 0; mb < 4; ++mb)
#pragma unroll
                for (int nb = 0; nb < 4; ++nb)
                    acc[mb][nb] = MFMA(a[mb], b[nb], acc[mb][nb]);
        }
    }
#pragma unroll
    for (int mb = 0; mb < 4; ++mb)
#pragma unroll
        for (int nb = 0; nb < 4; ++nb)
#pragma unroll
            for (int r2 = 0; r2 < 4; ++r2)
                C[(size_t)(m0 + wm * 64 + mb * 16 + lk * 4 + r2) * 1024 +
                  n0 + wn * 64 + nb * 16 + lr] = acc[mb][nb][r2];
}

// ---------------- Residual + LayerNorm ----------------
__global__ __launch_bounds__(256) void ln_kernel(const float* __restrict__ w,
                                                 const float* __restrict__ ao,
                                                 const float* __restrict__ gamma,
                                                 const float* __restrict__ beta,
                                                 float* __restrict__ out) {
    const int row = blockIdx.x;
    const int t = threadIdx.x;
    const size_t base = (size_t)row * 1024 + t * 4;
    const float4 xw = *(const float4*)(w + base);
    const float4 xa = *(const float4*)(ao + base);
    float x[4] = { xw.x + xa.x, xw.y + xa.y, xw.z + xa.z, xw.w + xa.w };
    float sum = x[0] + x[1] + x[2] + x[3];
    float sq  = x[0]*x[0] + x[1]*x[1] + x[2]*x[2] + x[3]*x[3];
#pragma unroll
    for (int off = 1; off < 64; off <<= 1) {
        sum += __shfl_xor(sum, off);
        sq  += __shfl_xor(sq, off);
    }
    __shared__ float ssum[4], ssq[4];
    const int wid = t >> 6;
    if ((t & 63) == 0) { ssum[wid] = sum; ssq[wid] = sq; }
    __syncthreads();
    sum = ssum[0] + ssum[1] + ssum[2] + ssum[3];
    sq  = ssq[0] + ssq[1] + ssq[2] + ssq[3];
    const float mu   = sum * (1.f / 1024.f);
    const float var  = sq * (1.f / 1024.f) - mu * mu;
    const float rstd = rsqrtf(var + 1e-5f);
    const float4 g4 = *(const float4*)(gamma + t * 4);
    const float4 b4 = *(const float4*)(beta + t * 4);
    float4 o;
    o.x = (x[0] - mu) * rstd * g4.x + b4.x;
    o.y = (x[1] - mu) * rstd * g4.y + b4.y;
    o.z = (x[2] - mu) * rstd * g4.z + b4.z;
    o.w = (x[3] - mu) * rstd * g4.w + b4.w;
    *(float4*)(out + base) = o;
}

extern "C" void kernel_launch(void* const* d_in, const int* in_sizes, int n_in,
                              void* d_out, int out_size, void* d_ws, size_t ws_size,
                              hipStream_t stream) {
    const float* w     = (const float*)d_in[0];
    const float* r     = (const float*)d_in[1];
    // d_in[2] attn_mask: deterministic causal mask, computed inline
    const float* Wqkv  = (const float*)d_in[3];
    const float* Wo    = (const float*)d_in[4];
    const float* gamma = (const float*)d_in[5];
    const float* beta  = (const float*)d_in[6];
    float* out = (float*)d_out;

    char* base = (char*)d_ws;
    ushort_t* A16  = (ushort_t*)(base + 0);           // [5248][1024]
    ushort_t* Bqt  = (ushort_t*)(base + 10747904);    // [3072][1024]
    ushort_t* Bot  = (ushort_t*)(base + 17039360);    // [1024][1024]
    ushort_t* Qp   = (ushort_t*)(base + 19136512);    // [(b,n)][1024][64]
    ushort_t* Kp   = (ushort_t*)(base + 27525120);
    ushort_t* Vp   = (ushort_t*)(base + 35913728);
    ushort_t* Vtp  = (ushort_t*)(base + 44302336);    // [(b,n)][64][1024]
    ushort_t* Rp   = (ushort_t*)(base + 52690944);    // [16][1216][64]
    float*    rq   = (float*)   (base + 55181312);    // [1024]
    ushort_t* av   = (ushort_t*)(base + 55185408);    // [4096][1024]
    float*    wsao = (float*)   (base + 63574016);    // [4096][1024]

    // zero Rp (incl. pads) + rq: 2490368 + 4096 bytes = 155904 uint4
    zero_fill<<<609, 256, 0, stream>>>((uint4*)Rp);
    cast_a<<<5248, 256, 0, stream>>>(w, r, A16);
    tcast<<<dim3(48, 16), 256, 0, stream>>>(Wqkv, Bqt, 1024, 3072);
    tcast<<<dim3(16, 16), 256, 0, stream>>>(Wo, Bot, 1024, 1024);
    rq_kernel<<<32, 256, 0, stream>>>(r, Wqkv, rq);
    gemm_qkv<<<840, 256, 0, stream>>>(A16, Bqt, rq, Qp, Kp, Vp, Rp);
    transpose_v<<<dim3(16, 64), 256, 0, stream>>>(Vp, Vtp);
    attn<<<512, 256, 0, stream>>>(Qp, Kp, Vtp, Rp, av);
    gemm_o<<<dim3(8, 32), 256, 0, stream>>>(av, Bot, wsao);
    ln_kernel<<<4096, 256, 0, stream>>>(w, wsao, gamma, beta, out);
}